// Round 4
// baseline (904.933 us; speedup 1.0000x reference)
//
#include <hip/hip_runtime.h>

#define BB 4096
#define SS 128
#define NB 16
#define NT 256
#define CS 32          // timesteps per chunk
#define NCH (SS/CS)    // 4 chunks

typedef __attribute__((ext_vector_type(8))) short short8;
typedef __attribute__((ext_vector_type(4))) float f32x4;
typedef unsigned short ushort_t;
typedef unsigned int uint_t;

#define SX_STR   72
#define SH1_STR  264
#define SEMB_STR 136
#define SH_STR   72

__device__ __forceinline__ ushort_t f2bf(float f) {
    union { float f; unsigned u; } x; x.f = f;
    unsigned r = x.u + 0x7FFFu + ((x.u >> 16) & 1u);
    return (ushort_t)(r >> 16);
}
__device__ __forceinline__ uint_t pack2(float a, float b) {
    return (uint_t)f2bf(a) | ((uint_t)f2bf(b) << 16);
}
__device__ __forceinline__ float bflo(uint_t u) {
    union { unsigned u; float f; } x; x.u = u << 16; return x.f;
}
__device__ __forceinline__ float bfhi(uint_t u) {
    union { unsigned u; float f; } x; x.u = u & 0xFFFF0000u; return x.f;
}
__device__ __forceinline__ float bf2f(ushort_t h) {
    union { unsigned u; float f; } x; x.u = ((unsigned)h) << 16; return x.f;
}
__device__ __forceinline__ float fsig(float x)  { return 1.f / (1.f + __expf(-x)); }
__device__ __forceinline__ float ftanh(float x) { return 1.f - 2.f / (__expf(2.f * x) + 1.f); }

union FragU { short8 v; ushort_t u[8]; };

// ============================================================================
// Prep: build bf16 B-fragment images for W1/W2/Wih/Whh in ws.
// frag f layout: img[f*64 + lane] = 8 bf16 (one dwordx4), element j -> k=kk*32+q*8+j.
// frag table: [0,32): W1  nt=f>>1, kk=f&1   (N=256, K=64 zero-padded from 47)
//             [32,96): W2 nt=(f-32)>>3, kk=(f-32)&7   (N=128, K=256)
//             [96,160): Wih nt=(f-96)>>2, kk=(f-96)&3 (N=256, K=128)
//             [160,192): Whh nt=(f-160)>>1, kk=(f-160)&1 (N=256, K=64)
// ============================================================================
__global__ void podcritic_prep(const float* __restrict__ W1, const float* __restrict__ W2,
                               const float* __restrict__ Wih, const float* __restrict__ Whh,
                               short8* __restrict__ img)
{
    const int W = blockIdx.x * 4 + (threadIdx.x >> 6);   // 0..191
    const int l = threadIdx.x & 63;
    const int q = l >> 4, m = l & 15;
    FragU u;
    #pragma unroll
    for (int j = 0; j < 8; ++j) {
        float v;
        if (W < 32)       { int nt = W >> 1,        kk = W & 1;        int k = kk*32 + q*8 + j;
                            v = (k < 47) ? W1[k*256 + nt*16 + m] : 0.f; }
        else if (W < 96)  { int f = W - 32, nt = f >> 3, kk = f & 7;   int k = kk*32 + q*8 + j;
                            v = W2[k*128 + nt*16 + m]; }
        else if (W < 160) { int f = W - 96, nt = f >> 2, kk = f & 3;   int k = kk*32 + q*8 + j;
                            v = Wih[k*256 + nt*16 + m]; }
        else              { int f = W - 160, nt = f >> 1, kk = f & 1;  int k = kk*32 + q*8 + j;
                            v = Whh[k*256 + nt*16 + m]; }
        u.u[j] = f2bf(v);
    }
    img[W * 64 + l] = u.v;
}

// ============================================================================
// Encoder v2: flat GEMM over 64 rows (4 steps x 16 batch) per block; 3 barriers.
// wx dword layout per (slc, bg): idx = tile_j*128 + lane*2 + {0,1}; value =
// bf16 pair of gates rows q*4+{0,1}/{2,3}, col 16*j+m (MFMA C layout).
// ============================================================================
__global__ __launch_bounds__(NT, 3)
void podcritic_enc2(const float* __restrict__ self_obs,
                    const float* __restrict__ tm_obs,
                    const float* __restrict__ en_obs,
                    const float* __restrict__ cp_obs,
                    const float* __restrict__ b1, const float* __restrict__ b2,
                    const float* __restrict__ bih, const float* __restrict__ bhh,
                    const short8* __restrict__ img,
                    uint_t* __restrict__ wx, int c0)
{
    __shared__ __align__(16) ushort_t sh1[64 * SH1_STR];   // 33.8 KB
    __shared__ __align__(16) ushort_t sxe[64 * SEMB_STR];  // union: sx (stride 72) then semb (stride 136)

    const int t = threadIdx.x;
    const int w = t >> 6, l = t & 63, q = l >> 4, m = l & 15;
    const int bg = blockIdx.x, b0 = bg * NB;
    const int sbase = c0 + blockIdx.y * 4;

    // gather x: 64 rows = (step mt 0..3) x (batch r 0..15); row rr = mt*16+r
    {
        const int col = t & 63, rw0 = t >> 6;
        #pragma unroll
        for (int jj = 0; jj < 16; ++jj) {
            int rr = 4 * jj + rw0;
            int mt = rr >> 4, r = rr & 15;
            int bs = (b0 + r) * SS + sbase + mt;
            float v = 0.f;
            if (col < 15)      v = self_obs[bs * 15 + col];
            else if (col < 28) v = tm_obs[bs * 13 + (col - 15)];
            else if (col < 41) { int k2 = col - 28;
                                 v = 0.5f * (en_obs[(bs * 2) * 13 + k2] + en_obs[(bs * 2) * 13 + 13 + k2]); }
            else if (col < 47) v = cp_obs[bs * 6 + (col - 41)];
            sxe[rr * SX_STR + col] = f2bf(v);
        }
    }
    float bias1[4], bias2[2], bgf[4];
    #pragma unroll
    for (int i = 0; i < 4; ++i) bias1[i] = b1[w * 64 + i * 16 + m];
    #pragma unroll
    for (int i = 0; i < 2; ++i) bias2[i] = b2[32 * w + 16 * i + m];
    #pragma unroll
    for (int i = 0; i < 4; ++i) { int n = (w + 4 * i) * 16 + m; bgf[i] = bih[n] + bhh[n]; }
    __syncthreads();

    // ---- phase 1: H1 = relu(x @ W1 + b1), M=64 ----
    {
        short8 w1f[4][2];
        #pragma unroll
        for (int i = 0; i < 4; ++i)
            #pragma unroll
            for (int kk = 0; kk < 2; ++kk)
                w1f[i][kk] = img[(((4 * w + i) * 2) + kk) * 64 + l];
        f32x4 c1[4][4];
        #pragma unroll
        for (int mt = 0; mt < 4; ++mt)
            #pragma unroll
            for (int i = 0; i < 4; ++i) c1[mt][i] = (f32x4){0.f, 0.f, 0.f, 0.f};
        #pragma unroll
        for (int kk = 0; kk < 2; ++kk) {
            #pragma unroll
            for (int mt = 0; mt < 4; ++mt) {
                short8 a = *(const short8*)&sxe[(mt * 16 + m) * SX_STR + kk * 32 + q * 8];
                #pragma unroll
                for (int i = 0; i < 4; ++i)
                    c1[mt][i] = __builtin_amdgcn_mfma_f32_16x16x32_bf16(a, w1f[i][kk], c1[mt][i], 0, 0, 0);
            }
        }
        #pragma unroll
        for (int mt = 0; mt < 4; ++mt)
            #pragma unroll
            for (int i = 0; i < 4; ++i) {
                int col = w * 64 + i * 16 + m;
                #pragma unroll
                for (int r = 0; r < 4; ++r)
                    sh1[(mt * 16 + q * 4 + r) * SH1_STR + col] = f2bf(fmaxf(c1[mt][i][r] + bias1[i], 0.f));
            }
    }
    __syncthreads();

    // ---- phase 2: EMB = relu(H1 @ W2 + b2), writes semb (aliases sx) ----
    {
        short8 w2f[2][8];
        #pragma unroll
        for (int i = 0; i < 2; ++i)
            #pragma unroll
            for (int kk = 0; kk < 8; ++kk)
                w2f[i][kk] = img[(32 + ((2 * w + i) * 8) + kk) * 64 + l];
        f32x4 c2[4][2];
        #pragma unroll
        for (int mt = 0; mt < 4; ++mt)
            #pragma unroll
            for (int i = 0; i < 2; ++i) c2[mt][i] = (f32x4){0.f, 0.f, 0.f, 0.f};
        #pragma unroll
        for (int kk = 0; kk < 8; ++kk) {
            #pragma unroll
            for (int mt = 0; mt < 4; ++mt) {
                short8 a = *(const short8*)&sh1[(mt * 16 + m) * SH1_STR + kk * 32 + q * 8];
                #pragma unroll
                for (int i = 0; i < 2; ++i)
                    c2[mt][i] = __builtin_amdgcn_mfma_f32_16x16x32_bf16(a, w2f[i][kk], c2[mt][i], 0, 0, 0);
            }
        }
        #pragma unroll
        for (int mt = 0; mt < 4; ++mt)
            #pragma unroll
            for (int i = 0; i < 2; ++i) {
                int col = 32 * w + 16 * i + m;
                #pragma unroll
                for (int r = 0; r < 4; ++r)
                    sxe[(mt * 16 + q * 4 + r) * SEMB_STR + col] = f2bf(fmaxf(c2[mt][i][r] + bias2[i], 0.f));
            }
    }
    __syncthreads();

    // ---- phase 3: wx = emb @ Wih + (bih+bhh), swizzled store; 2 Mtile halves ----
    {
        short8 wihf[4][4];
        #pragma unroll
        for (int i = 0; i < 4; ++i)
            #pragma unroll
            for (int kk = 0; kk < 4; ++kk)
                wihf[i][kk] = img[(96 + ((w + 4 * i) * 4) + kk) * 64 + l];
        #pragma unroll
        for (int half = 0; half < 2; ++half) {
            f32x4 g[2][4];
            #pragma unroll
            for (int mh = 0; mh < 2; ++mh)
                #pragma unroll
                for (int i = 0; i < 4; ++i) g[mh][i] = (f32x4){bgf[i], bgf[i], bgf[i], bgf[i]};
            #pragma unroll
            for (int kk = 0; kk < 4; ++kk) {
                #pragma unroll
                for (int mh = 0; mh < 2; ++mh) {
                    int mt = half * 2 + mh;
                    short8 a = *(const short8*)&sxe[(mt * 16 + m) * SEMB_STR + kk * 32 + q * 8];
                    #pragma unroll
                    for (int i = 0; i < 4; ++i)
                        g[mh][i] = __builtin_amdgcn_mfma_f32_16x16x32_bf16(a, wihf[i][kk], g[mh][i], 0, 0, 0);
                }
            }
            #pragma unroll
            for (int mh = 0; mh < 2; ++mh) {
                int slc = blockIdx.y * 4 + half * 2 + mh;
                uint_t* dst = wx + (size_t)(slc * 256 + bg) * 2048 + l * 2;
                #pragma unroll
                for (int i = 0; i < 4; ++i) {
                    uint2 vv;
                    vv.x = pack2(g[mh][i][0], g[mh][i][1]);
                    vv.y = pack2(g[mh][i][2], g[mh][i][3]);
                    *(uint2*)(dst + (w + 4 * i) * 128) = vv;
                }
            }
        }
    }
}

// ============================================================================
// Recurrence v2: ONE wave per 16 batch rows, barrier-free.
// Wave computes all 16 gate N-tiles (gates for its 16 rows x 256), does the
// full LSTM pointwise in-lane (16 cells: rows q*4+r, hid 16i+m), transposes h
// through its private LDS (same-wave DS ops are in-order -> no __syncthreads).
// ============================================================================
__global__ __launch_bounds__(64, 1)
void podcritic_rec2(const short8* __restrict__ whhimg,
                    const float* __restrict__ Wv, const float* __restrict__ bv,
                    const uint_t* __restrict__ wx,
                    uint_t* __restrict__ hws, float* __restrict__ cws,
                    float* __restrict__ out, int c0, int first, int last)
{
    __shared__ __align__(16) ushort_t sh[16 * SH_STR];

    const int l = threadIdx.x;            // 0..63
    const int q = l >> 4, m = l & 15;
    const int bg = blockIdx.x, b0 = bg * NB;

    short8 whhf[16][2];
    #pragma unroll
    for (int j = 0; j < 16; ++j)
        #pragma unroll
        for (int kk = 0; kk < 2; ++kk)
            whhf[j][kk] = whhimg[(j * 2 + kk) * 64 + l];

    float wv[4];
    #pragma unroll
    for (int i = 0; i < 4; ++i) wv[i] = Wv[16 * i + m];
    const float bvv = bv[0];

    float creg[16];
    if (first) {
        #pragma unroll
        for (int i = 0; i < 16; ++i) creg[i] = 0.f;
        #pragma unroll
        for (int i = 0; i < 4; ++i)
            #pragma unroll
            for (int r = 0; r < 4; ++r)
                sh[(q * 4 + r) * SH_STR + 16 * i + m] = 0;
    } else {
        uint4 hp0 = *(const uint4*)(hws + (size_t)bg * 512 + l * 8);
        uint4 hp1 = *(const uint4*)(hws + (size_t)bg * 512 + l * 8 + 4);
        uint_t hd[8] = {hp0.x, hp0.y, hp0.z, hp0.w, hp1.x, hp1.y, hp1.z, hp1.w};
        #pragma unroll
        for (int d = 0; d < 8; ++d) {
            int i = d >> 1, r0 = (d & 1) * 2;
            sh[(q * 4 + r0) * SH_STR + 16 * i + m]     = (ushort_t)(hd[d] & 0xFFFF);
            sh[(q * 4 + r0 + 1) * SH_STR + 16 * i + m] = (ushort_t)(hd[d] >> 16);
        }
        #pragma unroll
        for (int p = 0; p < 4; ++p) {
            float4 cv = *(const float4*)(cws + (size_t)bg * 1024 + l * 16 + 4 * p);
            creg[4 * p] = cv.x; creg[4 * p + 1] = cv.y; creg[4 * p + 2] = cv.z; creg[4 * p + 3] = cv.w;
        }
    }

    // prefetch wx for step 0
    uint2 upf[16];
    {
        const uint_t* base = wx + (size_t)bg * 2048 + l * 2;
        #pragma unroll
        for (int j = 0; j < 16; ++j) upf[j] = *(const uint2*)(base + j * 128);
    }

    float hv[4][4];
    for (int sl = 0; sl < CS; ++sl) {
        short8 af0 = *(const short8*)&sh[m * SH_STR + q * 8];
        short8 af1 = *(const short8*)&sh[m * SH_STR + 32 + q * 8];

        f32x4 g[16];
        #pragma unroll
        for (int j = 0; j < 16; ++j) {
            g[j][0] = bflo(upf[j].x); g[j][1] = bfhi(upf[j].x);
            g[j][2] = bflo(upf[j].y); g[j][3] = bfhi(upf[j].y);
        }
        // prefetch next step (upf dead after unpack)
        if (sl + 1 < CS) {
            const uint_t* base = wx + (size_t)((sl + 1) * 256 + bg) * 2048 + l * 2;
            #pragma unroll
            for (int j = 0; j < 16; ++j) upf[j] = *(const uint2*)(base + j * 128);
        }

        #pragma unroll
        for (int j = 0; j < 16; ++j) {
            g[j] = __builtin_amdgcn_mfma_f32_16x16x32_bf16(af0, whhf[j][0], g[j], 0, 0, 0);
            g[j] = __builtin_amdgcn_mfma_f32_16x16x32_bf16(af1, whhf[j][1], g[j], 0, 0, 0);
        }

        float pv[4] = {0.f, 0.f, 0.f, 0.f};
        #pragma unroll
        for (int i = 0; i < 4; ++i) {
            #pragma unroll
            for (int r = 0; r < 4; ++r) {
                float gi = fsig(g[i][r]);
                float gf = fsig(g[4 + i][r]);
                float gg = ftanh(g[8 + i][r]);
                float go = fsig(g[12 + i][r]);
                float c  = gf * creg[i * 4 + r] + gi * gg;
                creg[i * 4 + r] = c;
                float h = go * ftanh(c);
                hv[i][r] = h;
                pv[r] += h * wv[i];
                sh[(q * 4 + r) * SH_STR + 16 * i + m] = f2bf(h);
            }
        }
        #pragma unroll
        for (int mask = 1; mask <= 8; mask <<= 1) {
            #pragma unroll
            for (int r = 0; r < 4; ++r) pv[r] += __shfl_xor(pv[r], mask, 64);
        }
        if (m == 0) {
            #pragma unroll
            for (int r = 0; r < 4; ++r)
                out[(size_t)(b0 + q * 4 + r) * SS + (c0 + sl)] = pv[r] + bvv;
        }
    }

    if (!last) {
        uint_t hd[8];
        #pragma unroll
        for (int d = 0; d < 8; ++d) {
            int i = d >> 1, r0 = (d & 1) * 2;
            hd[d] = pack2(hv[i][r0], hv[i][r0 + 1]);
        }
        uint4 hp0 = {hd[0], hd[1], hd[2], hd[3]};
        uint4 hp1 = {hd[4], hd[5], hd[6], hd[7]};
        *(uint4*)(hws + (size_t)bg * 512 + l * 8)     = hp0;
        *(uint4*)(hws + (size_t)bg * 512 + l * 8 + 4) = hp1;
        #pragma unroll
        for (int p = 0; p < 4; ++p) {
            float4 cv; cv.x = creg[4 * p]; cv.y = creg[4 * p + 1];
            cv.z = creg[4 * p + 2]; cv.w = creg[4 * p + 3];
            *(float4*)(cws + (size_t)bg * 1024 + l * 16 + 4 * p) = cv;
        }
    } else {
        #pragma unroll
        for (int i = 0; i < 4; ++i)
            #pragma unroll
            for (int r = 0; r < 4; ++r) {
                int row = b0 + q * 4 + r;
                out[BB * SS + (size_t)row * 64 + 16 * i + m]           = hv[i][r];
                out[BB * SS + BB * 64 + (size_t)row * 64 + 16 * i + m] = creg[i * 4 + r];
            }
    }
}

// ============================================================================
// Fallback: round-2 fused kernel (used only if ws_size is too small)
// ============================================================================
__global__ __launch_bounds__(NT, 1)
void podcritic_mfma(const float* __restrict__ self_obs,
                    const float* __restrict__ tm_obs,
                    const float* __restrict__ en_obs,
                    const float* __restrict__ cp_obs,
                    const float* __restrict__ W1, const float* __restrict__ b1,
                    const float* __restrict__ W2, const float* __restrict__ b2,
                    const float* __restrict__ Wih, const float* __restrict__ bih,
                    const float* __restrict__ Whh, const float* __restrict__ bhh,
                    const float* __restrict__ Wv, const float* __restrict__ bv,
                    float* __restrict__ out)
{
    __shared__ __align__(16) ushort_t sx[2][NB * SX_STR];
    __shared__ __align__(16) ushort_t sh1[NB * SH1_STR];
    __shared__ __align__(16) ushort_t semb[NB * SEMB_STR];
    __shared__ __align__(16) ushort_t sh[NB * SH_STR];
    __shared__ float sWv[64];

    const int t  = threadIdx.x;
    const int w  = t >> 6;
    const int l  = t & 63;
    const int q  = l >> 4;
    const int m  = l & 15;
    const int b0 = blockIdx.x * NB;

    short8 w1f[4][2];
    short8 w2f[2][8];
    short8 wihf[4][4];
    short8 whhf[4][2];
    float bias1[4], bias2[2], bg[4];

    #pragma unroll
    for (int i = 0; i < 4; ++i) {
        int n = w * 64 + i * 16 + m;
        bias1[i] = b1[n];
        #pragma unroll
        for (int kk = 0; kk < 2; ++kk) {
            FragU u;
            #pragma unroll
            for (int j = 0; j < 8; ++j) {
                int k = kk * 32 + q * 8 + j;
                u.u[j] = f2bf(k < 47 ? W1[k * 256 + n] : 0.f);
            }
            w1f[i][kk] = u.v;
        }
    }
    #pragma unroll
    for (int i = 0; i < 2; ++i) {
        int n = 32 * w + i * 16 + m;
        bias2[i] = b2[n];
        #pragma unroll
        for (int kk = 0; kk < 8; ++kk) {
            FragU u;
            #pragma unroll
            for (int j = 0; j < 8; ++j) {
                int k = kk * 32 + q * 8 + j;
                u.u[j] = f2bf(W2[k * 128 + n]);
            }
            w2f[i][kk] = u.v;
        }
    }
    #pragma unroll
    for (int i = 0; i < 4; ++i) {
        int n = (w + 4 * i) * 16 + m;
        bg[i] = bih[n] + bhh[n];
        #pragma unroll
        for (int kk = 0; kk < 4; ++kk) {
            FragU u;
            #pragma unroll
            for (int j = 0; j < 8; ++j) {
                int k = kk * 32 + q * 8 + j;
                u.u[j] = f2bf(Wih[k * 256 + n]);
            }
            wihf[i][kk] = u.v;
        }
        #pragma unroll
        for (int kk = 0; kk < 2; ++kk) {
            FragU u;
            #pragma unroll
            for (int j = 0; j < 8; ++j) {
                int k = kk * 32 + q * 8 + j;
                u.u[j] = f2bf(Whh[k * 256 + n]);
            }
            whhf[i][kk] = u.v;
        }
    }
    const float bvv = bv[0];
    if (t < 64) sWv[t] = Wv[t];

    for (int idx = t; idx < NB * SH_STR; idx += NT) sh[idx] = 0;

    const int pcol = t & 63;
    const int prow = t >> 6;
    #pragma unroll
    for (int j = 0; j < 4; ++j) {
        int r  = 4 * j + prow;
        int bs = (b0 + r) * SS + 0;
        float v = 0.f;
        if (pcol < 15)      v = self_obs[bs * 15 + pcol];
        else if (pcol < 28) v = tm_obs[bs * 13 + (pcol - 15)];
        else if (pcol < 41) { int kk = pcol - 28;
                              v = 0.5f * (en_obs[(bs * 2) * 13 + kk] + en_obs[(bs * 2) * 13 + 13 + kk]); }
        else if (pcol < 47) v = cp_obs[bs * 6 + (pcol - 41)];
        sx[0][r * SX_STR + pcol] = f2bf(v);
    }
    __syncthreads();

    float creg[4] = {0.f, 0.f, 0.f, 0.f};
    float hreg[4] = {0.f, 0.f, 0.f, 0.f};
    int cur = 0;

    for (int s = 0; s < SS; ++s) {
        float pf[4];
        #pragma unroll
        for (int j = 0; j < 4; ++j) {
            float v = 0.f;
            if (s + 1 < SS) {
                int r  = 4 * j + prow;
                int bs = (b0 + r) * SS + (s + 1);
                if (pcol < 15)      v = self_obs[bs * 15 + pcol];
                else if (pcol < 28) v = tm_obs[bs * 13 + (pcol - 15)];
                else if (pcol < 41) { int kk = pcol - 28;
                                      v = 0.5f * (en_obs[(bs * 2) * 13 + kk] + en_obs[(bs * 2) * 13 + 13 + kk]); }
                else if (pcol < 47) v = cp_obs[bs * 6 + (pcol - 41)];
            }
            pf[j] = v;
        }

        {
            f32x4 c1[4] = {{0,0,0,0},{0,0,0,0},{0,0,0,0},{0,0,0,0}};
            #pragma unroll
            for (int kk = 0; kk < 2; ++kk) {
                short8 a = *(const short8*)&sx[cur][m * SX_STR + kk * 32 + q * 8];
                #pragma unroll
                for (int i = 0; i < 4; ++i)
                    c1[i] = __builtin_amdgcn_mfma_f32_16x16x32_bf16(a, w1f[i][kk], c1[i], 0, 0, 0);
            }
            #pragma unroll
            for (int i = 0; i < 4; ++i) {
                int col = w * 64 + i * 16 + m;
                #pragma unroll
                for (int r = 0; r < 4; ++r)
                    sh1[(q * 4 + r) * SH1_STR + col] = f2bf(fmaxf(c1[i][r] + bias1[i], 0.f));
            }
        }
        __syncthreads();

        {
            f32x4 c2[2] = {{0,0,0,0},{0,0,0,0}};
            #pragma unroll
            for (int kk = 0; kk < 8; ++kk) {
                short8 a = *(const short8*)&sh1[m * SH1_STR + kk * 32 + q * 8];
                #pragma unroll
                for (int i = 0; i < 2; ++i)
                    c2[i] = __builtin_amdgcn_mfma_f32_16x16x32_bf16(a, w2f[i][kk], c2[i], 0, 0, 0);
            }
            #pragma unroll
            for (int i = 0; i < 2; ++i) {
                int col = 32 * w + i * 16 + m;
                #pragma unroll
                for (int r = 0; r < 4; ++r)
                    semb[(q * 4 + r) * SEMB_STR + col] = f2bf(fmaxf(c2[i][r] + bias2[i], 0.f));
            }
        }
        __syncthreads();

        {
            f32x4 g[4];
            #pragma unroll
            for (int i = 0; i < 4; ++i) g[i] = (f32x4){bg[i], bg[i], bg[i], bg[i]};
            #pragma unroll
            for (int kk = 0; kk < 4; ++kk) {
                short8 a = *(const short8*)&semb[m * SEMB_STR + kk * 32 + q * 8];
                #pragma unroll
                for (int i = 0; i < 4; ++i)
                    g[i] = __builtin_amdgcn_mfma_f32_16x16x32_bf16(a, wihf[i][kk], g[i], 0, 0, 0);
            }
            #pragma unroll
            for (int kk = 0; kk < 2; ++kk) {
                short8 a = *(const short8*)&sh[m * SH_STR + kk * 32 + q * 8];
                #pragma unroll
                for (int i = 0; i < 4; ++i)
                    g[i] = __builtin_amdgcn_mfma_f32_16x16x32_bf16(a, whhf[i][kk], g[i], 0, 0, 0);
            }
            const int jcol = 16 * w + m;
            #pragma unroll
            for (int r = 0; r < 4; ++r) {
                float gi = fsig(g[0][r]);
                float gf = fsig(g[1][r]);
                float gg = ftanh(g[2][r]);
                float go = fsig(g[3][r]);
                float c  = gf * creg[r] + gi * gg;
                creg[r] = c;
                float h = go * ftanh(c);
                hreg[r] = h;
                sh[(q * 4 + r) * SH_STR + jcol] = f2bf(h);
            }
            #pragma unroll
            for (int j = 0; j < 4; ++j) {
                int r = 4 * j + prow;
                sx[cur ^ 1][r * SX_STR + pcol] = f2bf(pf[j]);
            }
        }
        __syncthreads();

        {
            int r = t >> 4, pp = t & 15;
            const ushort_t* hp = &sh[r * SH_STR + pp * 4];
            float pv = 0.f;
            #pragma unroll
            for (int j = 0; j < 4; ++j) pv += bf2f(hp[j]) * sWv[pp * 4 + j];
            pv += __shfl_xor(pv, 1, 16);
            pv += __shfl_xor(pv, 2, 16);
            pv += __shfl_xor(pv, 4, 16);
            pv += __shfl_xor(pv, 8, 16);
            if (pp == 0) out[(b0 + r) * SS + s] = pv + bvv;
        }
        cur ^= 1;
    }

    {
        const int jcol = 16 * w + m;
        #pragma unroll
        for (int r = 0; r < 4; ++r) {
            int row = b0 + q * 4 + r;
            out[BB * SS + row * 64 + jcol]           = hreg[r];
            out[BB * SS + BB * 64 + row * 64 + jcol] = creg[r];
        }
    }
}

extern "C" void kernel_launch(void* const* d_in, const int* in_sizes, int n_in,
                              void* d_out, int out_size, void* d_ws, size_t ws_size,
                              hipStream_t stream) {
    const float* self_obs = (const float*)d_in[0];
    const float* tm_obs   = (const float*)d_in[1];
    const float* en_obs   = (const float*)d_in[2];
    const float* cp_obs   = (const float*)d_in[3];
    const float* W1  = (const float*)d_in[4];
    const float* b1  = (const float*)d_in[5];
    const float* W2  = (const float*)d_in[6];
    const float* b2  = (const float*)d_in[7];
    const float* Wih = (const float*)d_in[8];
    const float* bih = (const float*)d_in[9];
    const float* Whh = (const float*)d_in[10];
    const float* bhh = (const float*)d_in[11];
    const float* Wv  = (const float*)d_in[12];
    const float* bv  = (const float*)d_in[13];
    float* out = (float*)d_out;

    const size_t wx_bytes  = (size_t)CS * 256 * 2048 * 4;   // 67,108,864
    const size_t h_bytes   = 256 * 512 * 4;                 // 524,288
    const size_t c_bytes   = 256 * 1024 * 4;                // 1,048,576
    const size_t img_bytes = 192 * 64 * 16;                 // 196,608
    const size_t need      = wx_bytes + h_bytes + c_bytes + img_bytes;

    if (ws_size >= need) {
        uint_t* wx   = (uint_t*)d_ws;
        uint_t* hws  = (uint_t*)((char*)d_ws + wx_bytes);
        float*  cws  = (float*)((char*)d_ws + wx_bytes + h_bytes);
        short8* img  = (short8*)((char*)d_ws + wx_bytes + h_bytes + c_bytes);
        const short8* whhimg = img + 160 * 64;

        podcritic_prep<<<48, NT, 0, stream>>>(W1, W2, Wih, Whh, img);
        for (int c = 0; c < NCH; ++c) {
            podcritic_enc2<<<dim3(256, 8), NT, 0, stream>>>(
                self_obs, tm_obs, en_obs, cp_obs,
                b1, b2, bih, bhh, img, wx, c * CS);
            podcritic_rec2<<<256, 64, 0, stream>>>(
                whhimg, Wv, bv, wx, hws, cws, out, c * CS,
                (c == 0) ? 1 : 0, (c == NCH - 1) ? 1 : 0);
        }
    } else {
        podcritic_mfma<<<BB / NB, NT, 0, stream>>>(
            self_obs, tm_obs, en_obs, cp_obs,
            W1, b1, W2, b2, Wih, bih, Whh, bhh, Wv, bv, out);
    }
}

// Round 5
// 626.858 us; speedup vs baseline: 1.4436x; 1.4436x over previous
//
#include <hip/hip_runtime.h>

#define BB 4096
#define SS 128
#define NB 16
#define NT 256
#define CS 32          // timesteps per chunk
#define NCH (SS/CS)    // 4 chunks

typedef __attribute__((ext_vector_type(8))) short short8;
typedef __attribute__((ext_vector_type(4))) float f32x4;
typedef unsigned short ushort_t;
typedef unsigned int uint_t;

#define SX_STR   72
#define SH1_STR  264
#define SEMB_STR 136
#define SH_STR   72

__device__ __forceinline__ ushort_t f2bf(float f) {
    union { float f; unsigned u; } x; x.f = f;
    unsigned r = x.u + 0x7FFFu + ((x.u >> 16) & 1u);
    return (ushort_t)(r >> 16);
}
__device__ __forceinline__ uint_t pack2(float a, float b) {
    return (uint_t)f2bf(a) | ((uint_t)f2bf(b) << 16);
}
__device__ __forceinline__ float bflo(uint_t u) {
    union { unsigned u; float f; } x; x.u = u << 16; return x.f;
}
__device__ __forceinline__ float bfhi(uint_t u) {
    union { unsigned u; float f; } x; x.u = u & 0xFFFF0000u; return x.f;
}
__device__ __forceinline__ float bf2f(ushort_t h) {
    union { unsigned u; float f; } x; x.u = ((unsigned)h) << 16; return x.f;
}
__device__ __forceinline__ float fsig(float x)  { return 1.f / (1.f + __expf(-x)); }
__device__ __forceinline__ float ftanh(float x) { return 1.f - 2.f / (__expf(2.f * x) + 1.f); }

// workgroup barrier WITHOUT vmcnt drain: LDS ordering only. Keeps the wx
// prefetch (global loads) in flight across the step boundary.
__device__ __forceinline__ void barrier_lgkm() {
    asm volatile("s_waitcnt lgkmcnt(0)\n\ts_barrier" ::: "memory");
}

union FragU { short8 v; ushort_t u[8]; };

// ============================================================================
// Prep: build bf16 B-fragment images for W1/W2/Wih/Whh in ws.
// ============================================================================
__global__ void podcritic_prep(const float* __restrict__ W1, const float* __restrict__ W2,
                               const float* __restrict__ Wih, const float* __restrict__ Whh,
                               short8* __restrict__ img)
{
    const int W = blockIdx.x * 4 + (threadIdx.x >> 6);   // 0..191
    const int l = threadIdx.x & 63;
    const int q = l >> 4, m = l & 15;
    FragU u;
    #pragma unroll
    for (int j = 0; j < 8; ++j) {
        float v;
        if (W < 32)       { int nt = W >> 1,        kk = W & 1;        int k = kk*32 + q*8 + j;
                            v = (k < 47) ? W1[k*256 + nt*16 + m] : 0.f; }
        else if (W < 96)  { int f = W - 32, nt = f >> 3, kk = f & 7;   int k = kk*32 + q*8 + j;
                            v = W2[k*128 + nt*16 + m]; }
        else if (W < 160) { int f = W - 96, nt = f >> 2, kk = f & 3;   int k = kk*32 + q*8 + j;
                            v = Wih[k*256 + nt*16 + m]; }
        else              { int f = W - 160, nt = f >> 1, kk = f & 1;  int k = kk*32 + q*8 + j;
                            v = Whh[k*256 + nt*16 + m]; }
        u.u[j] = f2bf(v);
    }
    img[W * 64 + l] = u.v;
}

// ============================================================================
// Encoder: flat GEMM over 64 rows (4 steps x 16 batch) per block; 3 barriers.
// wx dword layout per (slc, bg): idx = tile_j*128 + lane*2 + {0,1} (MFMA C).
// ============================================================================
__global__ __launch_bounds__(NT, 3)
void podcritic_enc2(const float* __restrict__ self_obs,
                    const float* __restrict__ tm_obs,
                    const float* __restrict__ en_obs,
                    const float* __restrict__ cp_obs,
                    const float* __restrict__ b1, const float* __restrict__ b2,
                    const float* __restrict__ bih, const float* __restrict__ bhh,
                    const short8* __restrict__ img,
                    uint_t* __restrict__ wx, int c0)
{
    __shared__ __align__(16) ushort_t sh1[64 * SH1_STR];
    __shared__ __align__(16) ushort_t sxe[64 * SEMB_STR];

    const int t = threadIdx.x;
    const int w = t >> 6, l = t & 63, q = l >> 4, m = l & 15;
    const int bg = blockIdx.x, b0 = bg * NB;
    const int sbase = c0 + blockIdx.y * 4;

    {
        const int col = t & 63, rw0 = t >> 6;
        #pragma unroll
        for (int jj = 0; jj < 16; ++jj) {
            int rr = 4 * jj + rw0;
            int mt = rr >> 4, r = rr & 15;
            int bs = (b0 + r) * SS + sbase + mt;
            float v = 0.f;
            if (col < 15)      v = self_obs[bs * 15 + col];
            else if (col < 28) v = tm_obs[bs * 13 + (col - 15)];
            else if (col < 41) { int k2 = col - 28;
                                 v = 0.5f * (en_obs[(bs * 2) * 13 + k2] + en_obs[(bs * 2) * 13 + 13 + k2]); }
            else if (col < 47) v = cp_obs[bs * 6 + (col - 41)];
            sxe[rr * SX_STR + col] = f2bf(v);
        }
    }
    float bias1[4], bias2[2], bgf[4];
    #pragma unroll
    for (int i = 0; i < 4; ++i) bias1[i] = b1[w * 64 + i * 16 + m];
    #pragma unroll
    for (int i = 0; i < 2; ++i) bias2[i] = b2[32 * w + 16 * i + m];
    #pragma unroll
    for (int i = 0; i < 4; ++i) { int n = (w + 4 * i) * 16 + m; bgf[i] = bih[n] + bhh[n]; }
    __syncthreads();

    // ---- phase 1: H1 = relu(x @ W1 + b1), M=64 ----
    {
        short8 w1f[4][2];
        #pragma unroll
        for (int i = 0; i < 4; ++i)
            #pragma unroll
            for (int kk = 0; kk < 2; ++kk)
                w1f[i][kk] = img[(((4 * w + i) * 2) + kk) * 64 + l];
        f32x4 c1[4][4];
        #pragma unroll
        for (int mt = 0; mt < 4; ++mt)
            #pragma unroll
            for (int i = 0; i < 4; ++i) c1[mt][i] = (f32x4){0.f, 0.f, 0.f, 0.f};
        #pragma unroll
        for (int kk = 0; kk < 2; ++kk) {
            #pragma unroll
            for (int mt = 0; mt < 4; ++mt) {
                short8 a = *(const short8*)&sxe[(mt * 16 + m) * SX_STR + kk * 32 + q * 8];
                #pragma unroll
                for (int i = 0; i < 4; ++i)
                    c1[mt][i] = __builtin_amdgcn_mfma_f32_16x16x32_bf16(a, w1f[i][kk], c1[mt][i], 0, 0, 0);
            }
        }
        #pragma unroll
        for (int mt = 0; mt < 4; ++mt)
            #pragma unroll
            for (int i = 0; i < 4; ++i) {
                int col = w * 64 + i * 16 + m;
                #pragma unroll
                for (int r = 0; r < 4; ++r)
                    sh1[(mt * 16 + q * 4 + r) * SH1_STR + col] = f2bf(fmaxf(c1[mt][i][r] + bias1[i], 0.f));
            }
    }
    __syncthreads();

    // ---- phase 2: EMB = relu(H1 @ W2 + b2) ----
    {
        short8 w2f[2][8];
        #pragma unroll
        for (int i = 0; i < 2; ++i)
            #pragma unroll
            for (int kk = 0; kk < 8; ++kk)
                w2f[i][kk] = img[(32 + ((2 * w + i) * 8) + kk) * 64 + l];
        f32x4 c2[4][2];
        #pragma unroll
        for (int mt = 0; mt < 4; ++mt)
            #pragma unroll
            for (int i = 0; i < 2; ++i) c2[mt][i] = (f32x4){0.f, 0.f, 0.f, 0.f};
        #pragma unroll
        for (int kk = 0; kk < 8; ++kk) {
            #pragma unroll
            for (int mt = 0; mt < 4; ++mt) {
                short8 a = *(const short8*)&sh1[(mt * 16 + m) * SH1_STR + kk * 32 + q * 8];
                #pragma unroll
                for (int i = 0; i < 2; ++i)
                    c2[mt][i] = __builtin_amdgcn_mfma_f32_16x16x32_bf16(a, w2f[i][kk], c2[mt][i], 0, 0, 0);
            }
        }
        #pragma unroll
        for (int mt = 0; mt < 4; ++mt)
            #pragma unroll
            for (int i = 0; i < 2; ++i) {
                int col = 32 * w + 16 * i + m;
                #pragma unroll
                for (int r = 0; r < 4; ++r)
                    sxe[(mt * 16 + q * 4 + r) * SEMB_STR + col] = f2bf(fmaxf(c2[mt][i][r] + bias2[i], 0.f));
            }
    }
    __syncthreads();

    // ---- phase 3: wx = emb @ Wih + (bih+bhh), swizzled store ----
    {
        short8 wihf[4][4];
        #pragma unroll
        for (int i = 0; i < 4; ++i)
            #pragma unroll
            for (int kk = 0; kk < 4; ++kk)
                wihf[i][kk] = img[(96 + ((w + 4 * i) * 4) + kk) * 64 + l];
        #pragma unroll
        for (int half = 0; half < 2; ++half) {
            f32x4 g[2][4];
            #pragma unroll
            for (int mh = 0; mh < 2; ++mh)
                #pragma unroll
                for (int i = 0; i < 4; ++i) g[mh][i] = (f32x4){bgf[i], bgf[i], bgf[i], bgf[i]};
            #pragma unroll
            for (int kk = 0; kk < 4; ++kk) {
                #pragma unroll
                for (int mh = 0; mh < 2; ++mh) {
                    int mt = half * 2 + mh;
                    short8 a = *(const short8*)&sxe[(mt * 16 + m) * SEMB_STR + kk * 32 + q * 8];
                    #pragma unroll
                    for (int i = 0; i < 4; ++i)
                        g[mh][i] = __builtin_amdgcn_mfma_f32_16x16x32_bf16(a, wihf[i][kk], g[mh][i], 0, 0, 0);
                }
            }
            #pragma unroll
            for (int mh = 0; mh < 2; ++mh) {
                int slc = blockIdx.y * 4 + half * 2 + mh;
                uint_t* dst = wx + (size_t)(slc * 256 + bg) * 2048 + l * 2;
                #pragma unroll
                for (int i = 0; i < 4; ++i) {
                    uint2 vv;
                    vv.x = pack2(g[mh][i][0], g[mh][i][1]);
                    vv.y = pack2(g[mh][i][2], g[mh][i][3]);
                    *(uint2*)(dst + (w + 4 * i) * 128) = vv;
                }
            }
        }
    }
}

// ============================================================================
// Recurrence v3: 4 waves per 16 batch rows. Wave w owns gate tiles
// {w, w+4, w+8, w+12} = i,f,g,o for hidden units 16w+m -> 4 cells/lane.
// lgkm-only barrier per step (wx prefetch stays in flight), 2-deep prefetch.
// ============================================================================
__global__ __launch_bounds__(NT, 1)
void podcritic_rec3(const short8* __restrict__ whhimg,
                    const float* __restrict__ Wv, const float* __restrict__ bv,
                    const uint_t* __restrict__ wx,
                    ushort_t* __restrict__ hws, float* __restrict__ cws,
                    float* __restrict__ out, int c0, int first, int last)
{
    __shared__ __align__(16) ushort_t sh[2][NB * SH_STR];
    __shared__ float sval[2][64];

    const int t  = threadIdx.x;
    const int w  = t >> 6, l = t & 63, q = l >> 4, m = l & 15;
    const int bg = blockIdx.x, b0 = bg * NB;

    short8 whhf[4][2];
    #pragma unroll
    for (int a = 0; a < 4; ++a)
        #pragma unroll
        for (int kk = 0; kk < 2; ++kk)
            whhf[a][kk] = whhimg[(((w + 4 * a) * 2) + kk) * 64 + l];

    const float wv  = Wv[16 * w + m];
    const float bvv = bv[0];

    float creg[4], hlast[4] = {0.f, 0.f, 0.f, 0.f};
    // init sh[0] (h state) and creg
    if (first) {
        #pragma unroll
        for (int r = 0; r < 4; ++r) creg[r] = 0.f;
        int idx4 = t * 4, row = idx4 >> 6, col = idx4 & 63;
        uint2 z; z.x = 0u; z.y = 0u;
        *(uint2*)&sh[0][row * SH_STR + col] = z;
    } else {
        int idx4 = t * 4, row = idx4 >> 6, col = idx4 & 63;
        uint2 hv2 = *(const uint2*)((const uint_t*)(hws + (size_t)bg * 1024 + idx4));
        *(uint2*)&sh[0][row * SH_STR + col] = hv2;
        float4 cv = *(const float4*)(cws + ((size_t)bg * 256 + t) * 4);
        creg[0] = cv.x; creg[1] = cv.y; creg[2] = cv.z; creg[3] = cv.w;
    }

    // 2-deep wx prefetch ring: upf[parity][tile]
    uint2 upf[2][4];
    {
        const uint_t* p0 = wx + (size_t)(0 * 256 + bg) * 2048 + l * 2;
        const uint_t* p1 = wx + (size_t)(1 * 256 + bg) * 2048 + l * 2;
        #pragma unroll
        for (int a = 0; a < 4; ++a) {
            upf[0][a] = *(const uint2*)(p0 + (w + 4 * a) * 128);
            upf[1][a] = *(const uint2*)(p1 + (w + 4 * a) * 128);
        }
    }
    barrier_lgkm();

    #pragma unroll 2
    for (int sl = 0; sl < CS; ++sl) {
        const int par = sl & 1;

        // A-frags: h(sl) from sh[par]
        short8 af0 = *(const short8*)&sh[par][m * SH_STR + q * 8];
        short8 af1 = *(const short8*)&sh[par][m * SH_STR + 32 + q * 8];

        // gate init from prefetched wx (wx already contains all biases)
        f32x4 g[4];
        #pragma unroll
        for (int a = 0; a < 4; ++a) {
            g[a][0] = bflo(upf[par][a].x); g[a][1] = bfhi(upf[par][a].x);
            g[a][2] = bflo(upf[par][a].y); g[a][3] = bfhi(upf[par][a].y);
        }

        // refill this parity slot with wx(sl+2)
        {
            int snext = (sl + 2 < CS) ? (sl + 2) : sl;
            const uint_t* pn = wx + (size_t)(snext * 256 + bg) * 2048 + l * 2;
            #pragma unroll
            for (int a = 0; a < 4; ++a)
                upf[par][a] = *(const uint2*)(pn + (w + 4 * a) * 128);
        }

        #pragma unroll
        for (int a = 0; a < 4; ++a) {
            g[a] = __builtin_amdgcn_mfma_f32_16x16x32_bf16(af0, whhf[a][0], g[a], 0, 0, 0);
            g[a] = __builtin_amdgcn_mfma_f32_16x16x32_bf16(af1, whhf[a][1], g[a], 0, 0, 0);
        }

        // pointwise: 4 cells per lane (rows q*4+r, hidden 16w+m)
        float pv[4];
        #pragma unroll
        for (int r = 0; r < 4; ++r) {
            float gi = fsig(g[0][r]);
            float gf = fsig(g[1][r]);
            float gg = ftanh(g[2][r]);
            float go = fsig(g[3][r]);
            float c  = gf * creg[r] + gi * gg;
            creg[r] = c;
            float h = go * ftanh(c);
            hlast[r] = h;
            sh[par ^ 1][(q * 4 + r) * SH_STR + 16 * w + m] = f2bf(h);
            pv[r] = h * wv;
        }
        // per-wave reduce over the 16 m-lanes
        #pragma unroll
        for (int mask = 1; mask <= 8; mask <<= 1) {
            #pragma unroll
            for (int r = 0; r < 4; ++r) pv[r] += __shfl_xor(pv[r], mask, 64);
        }
        if (m == 0) {
            #pragma unroll
            for (int r = 0; r < 4; ++r) sval[par][w * 16 + 4 * q + r] = pv[r];
        }

        barrier_lgkm();

        if (t < 16)
            out[(size_t)(b0 + t) * SS + (c0 + sl)] =
                sval[par][t] + sval[par][16 + t] + sval[par][32 + t] + sval[par][48 + t] + bvv;
    }

    if (!last) {
        const int jcol = 16 * w + m;
        #pragma unroll
        for (int r = 0; r < 4; ++r)
            hws[(size_t)bg * 1024 + (q * 4 + r) * 64 + jcol] = f2bf(hlast[r]);
        float4 cv; cv.x = creg[0]; cv.y = creg[1]; cv.z = creg[2]; cv.w = creg[3];
        *(float4*)(cws + ((size_t)bg * 256 + t) * 4) = cv;
    } else {
        const int jcol = 16 * w + m;
        #pragma unroll
        for (int r = 0; r < 4; ++r) {
            int row = b0 + q * 4 + r;
            out[BB * SS + (size_t)row * 64 + jcol]           = hlast[r];
            out[BB * SS + BB * 64 + (size_t)row * 64 + jcol] = creg[r];
        }
    }
}

// ============================================================================
// Fallback: round-2 fused kernel (used only if ws_size is too small)
// ============================================================================
__global__ __launch_bounds__(NT, 1)
void podcritic_mfma(const float* __restrict__ self_obs,
                    const float* __restrict__ tm_obs,
                    const float* __restrict__ en_obs,
                    const float* __restrict__ cp_obs,
                    const float* __restrict__ W1, const float* __restrict__ b1,
                    const float* __restrict__ W2, const float* __restrict__ b2,
                    const float* __restrict__ Wih, const float* __restrict__ bih,
                    const float* __restrict__ Whh, const float* __restrict__ bhh,
                    const float* __restrict__ Wv, const float* __restrict__ bv,
                    float* __restrict__ out)
{
    __shared__ __align__(16) ushort_t sx[2][NB * SX_STR];
    __shared__ __align__(16) ushort_t sh1[NB * SH1_STR];
    __shared__ __align__(16) ushort_t semb[NB * SEMB_STR];
    __shared__ __align__(16) ushort_t sh[NB * SH_STR];
    __shared__ float sWv[64];

    const int t  = threadIdx.x;
    const int w  = t >> 6;
    const int l  = t & 63;
    const int q  = l >> 4;
    const int m  = l & 15;
    const int b0 = blockIdx.x * NB;

    short8 w1f[4][2];
    short8 w2f[2][8];
    short8 wihf[4][4];
    short8 whhf[4][2];
    float bias1[4], bias2[2], bg[4];

    #pragma unroll
    for (int i = 0; i < 4; ++i) {
        int n = w * 64 + i * 16 + m;
        bias1[i] = b1[n];
        #pragma unroll
        for (int kk = 0; kk < 2; ++kk) {
            FragU u;
            #pragma unroll
            for (int j = 0; j < 8; ++j) {
                int k = kk * 32 + q * 8 + j;
                u.u[j] = f2bf(k < 47 ? W1[k * 256 + n] : 0.f);
            }
            w1f[i][kk] = u.v;
        }
    }
    #pragma unroll
    for (int i = 0; i < 2; ++i) {
        int n = 32 * w + i * 16 + m;
        bias2[i] = b2[n];
        #pragma unroll
        for (int kk = 0; kk < 8; ++kk) {
            FragU u;
            #pragma unroll
            for (int j = 0; j < 8; ++j) {
                int k = kk * 32 + q * 8 + j;
                u.u[j] = f2bf(W2[k * 128 + n]);
            }
            w2f[i][kk] = u.v;
        }
    }
    #pragma unroll
    for (int i = 0; i < 4; ++i) {
        int n = (w + 4 * i) * 16 + m;
        bg[i] = bih[n] + bhh[n];
        #pragma unroll
        for (int kk = 0; kk < 4; ++kk) {
            FragU u;
            #pragma unroll
            for (int j = 0; j < 8; ++j) {
                int k = kk * 32 + q * 8 + j;
                u.u[j] = f2bf(Wih[k * 256 + n]);
            }
            wihf[i][kk] = u.v;
        }
        #pragma unroll
        for (int kk = 0; kk < 2; ++kk) {
            FragU u;
            #pragma unroll
            for (int j = 0; j < 8; ++j) {
                int k = kk * 32 + q * 8 + j;
                u.u[j] = f2bf(Whh[k * 256 + n]);
            }
            whhf[i][kk] = u.v;
        }
    }
    const float bvv = bv[0];
    if (t < 64) sWv[t] = Wv[t];

    for (int idx = t; idx < NB * SH_STR; idx += NT) sh[idx] = 0;

    const int pcol = t & 63;
    const int prow = t >> 6;
    #pragma unroll
    for (int j = 0; j < 4; ++j) {
        int r  = 4 * j + prow;
        int bs = (b0 + r) * SS + 0;
        float v = 0.f;
        if (pcol < 15)      v = self_obs[bs * 15 + pcol];
        else if (pcol < 28) v = tm_obs[bs * 13 + (pcol - 15)];
        else if (pcol < 41) { int kk = pcol - 28;
                              v = 0.5f * (en_obs[(bs * 2) * 13 + kk] + en_obs[(bs * 2) * 13 + 13 + kk]); }
        else if (pcol < 47) v = cp_obs[bs * 6 + (pcol - 41)];
        sx[0][r * SX_STR + pcol] = f2bf(v);
    }
    __syncthreads();

    float creg[4] = {0.f, 0.f, 0.f, 0.f};
    float hreg[4] = {0.f, 0.f, 0.f, 0.f};
    int cur = 0;

    for (int s = 0; s < SS; ++s) {
        float pf[4];
        #pragma unroll
        for (int j = 0; j < 4; ++j) {
            float v = 0.f;
            if (s + 1 < SS) {
                int r  = 4 * j + prow;
                int bs = (b0 + r) * SS + (s + 1);
                if (pcol < 15)      v = self_obs[bs * 15 + pcol];
                else if (pcol < 28) v = tm_obs[bs * 13 + (pcol - 15)];
                else if (pcol < 41) { int kk = pcol - 28;
                                      v = 0.5f * (en_obs[(bs * 2) * 13 + kk] + en_obs[(bs * 2) * 13 + 13 + kk]); }
                else if (pcol < 47) v = cp_obs[bs * 6 + (pcol - 41)];
            }
            pf[j] = v;
        }

        {
            f32x4 c1[4] = {{0,0,0,0},{0,0,0,0},{0,0,0,0},{0,0,0,0}};
            #pragma unroll
            for (int kk = 0; kk < 2; ++kk) {
                short8 a = *(const short8*)&sx[cur][m * SX_STR + kk * 32 + q * 8];
                #pragma unroll
                for (int i = 0; i < 4; ++i)
                    c1[i] = __builtin_amdgcn_mfma_f32_16x16x32_bf16(a, w1f[i][kk], c1[i], 0, 0, 0);
            }
            #pragma unroll
            for (int i = 0; i < 4; ++i) {
                int col = w * 64 + i * 16 + m;
                #pragma unroll
                for (int r = 0; r < 4; ++r)
                    sh1[(q * 4 + r) * SH1_STR + col] = f2bf(fmaxf(c1[i][r] + bias1[i], 0.f));
            }
        }
        __syncthreads();

        {
            f32x4 c2[2] = {{0,0,0,0},{0,0,0,0}};
            #pragma unroll
            for (int kk = 0; kk < 8; ++kk) {
                short8 a = *(const short8*)&sh1[m * SH1_STR + kk * 32 + q * 8];
                #pragma unroll
                for (int i = 0; i < 2; ++i)
                    c2[i] = __builtin_amdgcn_mfma_f32_16x16x32_bf16(a, w2f[i][kk], c2[i], 0, 0, 0);
            }
            #pragma unroll
            for (int i = 0; i < 2; ++i) {
                int col = 32 * w + i * 16 + m;
                #pragma unroll
                for (int r = 0; r < 4; ++r)
                    semb[(q * 4 + r) * SEMB_STR + col] = f2bf(fmaxf(c2[i][r] + bias2[i], 0.f));
            }
        }
        __syncthreads();

        {
            f32x4 g[4];
            #pragma unroll
            for (int i = 0; i < 4; ++i) g[i] = (f32x4){bg[i], bg[i], bg[i], bg[i]};
            #pragma unroll
            for (int kk = 0; kk < 4; ++kk) {
                short8 a = *(const short8*)&semb[m * SEMB_STR + kk * 32 + q * 8];
                #pragma unroll
                for (int i = 0; i < 4; ++i)
                    g[i] = __builtin_amdgcn_mfma_f32_16x16x32_bf16(a, wihf[i][kk], g[i], 0, 0, 0);
            }
            #pragma unroll
            for (int kk = 0; kk < 2; ++kk) {
                short8 a = *(const short8*)&sh[m * SH_STR + kk * 32 + q * 8];
                #pragma unroll
                for (int i = 0; i < 4; ++i)
                    g[i] = __builtin_amdgcn_mfma_f32_16x16x32_bf16(a, whhf[i][kk], g[i], 0, 0, 0);
            }
            const int jcol = 16 * w + m;
            #pragma unroll
            for (int r = 0; r < 4; ++r) {
                float gi = fsig(g[0][r]);
                float gf = fsig(g[1][r]);
                float gg = ftanh(g[2][r]);
                float go = fsig(g[3][r]);
                float c  = gf * creg[r] + gi * gg;
                creg[r] = c;
                float h = go * ftanh(c);
                hreg[r] = h;
                sh[(q * 4 + r) * SH_STR + jcol] = f2bf(h);
            }
            #pragma unroll
            for (int j = 0; j < 4; ++j) {
                int r = 4 * j + prow;
                sx[cur ^ 1][r * SX_STR + pcol] = f2bf(pf[j]);
            }
        }
        __syncthreads();

        {
            int r = t >> 4, pp = t & 15;
            const ushort_t* hp = &sh[r * SH_STR + pp * 4];
            float pv = 0.f;
            #pragma unroll
            for (int j = 0; j < 4; ++j) pv += bf2f(hp[j]) * sWv[pp * 4 + j];
            pv += __shfl_xor(pv, 1, 16);
            pv += __shfl_xor(pv, 2, 16);
            pv += __shfl_xor(pv, 4, 16);
            pv += __shfl_xor(pv, 8, 16);
            if (pp == 0) out[(b0 + r) * SS + s] = pv + bvv;
        }
        cur ^= 1;
    }

    {
        const int jcol = 16 * w + m;
        #pragma unroll
        for (int r = 0; r < 4; ++r) {
            int row = b0 + q * 4 + r;
            out[BB * SS + row * 64 + jcol]           = hreg[r];
            out[BB * SS + BB * 64 + row * 64 + jcol] = creg[r];
        }
    }
}

extern "C" void kernel_launch(void* const* d_in, const int* in_sizes, int n_in,
                              void* d_out, int out_size, void* d_ws, size_t ws_size,
                              hipStream_t stream) {
    const float* self_obs = (const float*)d_in[0];
    const float* tm_obs   = (const float*)d_in[1];
    const float* en_obs   = (const float*)d_in[2];
    const float* cp_obs   = (const float*)d_in[3];
    const float* W1  = (const float*)d_in[4];
    const float* b1  = (const float*)d_in[5];
    const float* W2  = (const float*)d_in[6];
    const float* b2  = (const float*)d_in[7];
    const float* Wih = (const float*)d_in[8];
    const float* bih = (const float*)d_in[9];
    const float* Whh = (const float*)d_in[10];
    const float* bhh = (const float*)d_in[11];
    const float* Wv  = (const float*)d_in[12];
    const float* bv  = (const float*)d_in[13];
    float* out = (float*)d_out;

    const size_t wx_bytes  = (size_t)CS * 256 * 2048 * 4;   // 67,108,864
    const size_t h_bytes   = 256 * 1024 * 2;                // 524,288
    const size_t c_bytes   = 256 * 1024 * 4;                // 1,048,576
    const size_t img_bytes = 192 * 64 * 16;                 // 196,608
    const size_t need      = wx_bytes + h_bytes + c_bytes + img_bytes;

    if (ws_size >= need) {
        uint_t*   wx  = (uint_t*)d_ws;
        ushort_t* hws = (ushort_t*)((char*)d_ws + wx_bytes);
        float*    cws = (float*)((char*)d_ws + wx_bytes + h_bytes);
        short8*   img = (short8*)((char*)d_ws + wx_bytes + h_bytes + c_bytes);
        const short8* whhimg = img + 160 * 64;

        podcritic_prep<<<48, NT, 0, stream>>>(W1, W2, Wih, Whh, img);
        for (int c = 0; c < NCH; ++c) {
            podcritic_enc2<<<dim3(256, 8), NT, 0, stream>>>(
                self_obs, tm_obs, en_obs, cp_obs,
                b1, b2, bih, bhh, img, wx, c * CS);
            podcritic_rec3<<<256, NT, 0, stream>>>(
                whhimg, Wv, bv, wx, hws, cws, out, c * CS,
                (c == 0) ? 1 : 0, (c == NCH - 1) ? 1 : 0);
        }
    } else {
        podcritic_mfma<<<BB / NB, NT, 0, stream>>>(
            self_obs, tm_obs, en_obs, cp_obs,
            W1, b1, W2, b2, Wih, bih, Whh, bhh, Wv, bv, out);
    }
}

// Round 6
// 605.087 us; speedup vs baseline: 1.4955x; 1.0360x over previous
//
#include <hip/hip_runtime.h>

#define BB 4096
#define SS 128
#define NB 16
#define NT 256
#define CS 32          // timesteps per chunk
#define NCH (SS/CS)    // 4 chunks

typedef __attribute__((ext_vector_type(8))) short short8;
typedef __attribute__((ext_vector_type(4))) float f32x4;
typedef unsigned short ushort_t;
typedef unsigned int uint_t;

#define SX_STR   72
#define SH1_STR  264
#define SEMB_STR 136
#define SH_STR   72

__device__ __forceinline__ ushort_t f2bf(float f) {
    union { float f; unsigned u; } x; x.f = f;
    unsigned r = x.u + 0x7FFFu + ((x.u >> 16) & 1u);
    return (ushort_t)(r >> 16);
}
__device__ __forceinline__ uint_t pack2(float a, float b) {
    return (uint_t)f2bf(a) | ((uint_t)f2bf(b) << 16);
}
__device__ __forceinline__ float bflo(uint_t u) {
    union { unsigned u; float f; } x; x.u = u << 16; return x.f;
}
__device__ __forceinline__ float bfhi(uint_t u) {
    union { unsigned u; float f; } x; x.u = u & 0xFFFF0000u; return x.f;
}
__device__ __forceinline__ float bf2f(ushort_t h) {
    union { unsigned u; float f; } x; x.u = ((unsigned)h) << 16; return x.f;
}
__device__ __forceinline__ float fsig(float x)  { return 1.f / (1.f + __expf(-x)); }
__device__ __forceinline__ float ftanh(float x) { return 1.f - 2.f / (__expf(2.f * x) + 1.f); }

// workgroup barrier WITHOUT vmcnt drain: LDS ordering only.
__device__ __forceinline__ void barrier_lgkm() {
    asm volatile("s_waitcnt lgkmcnt(0)\n\ts_barrier" ::: "memory");
}

union FragU { short8 v; ushort_t u[8]; };

// ============================================================================
// Prep: build bf16 B-fragment images for W1/W2/Wih/Whh in ws.
// ============================================================================
__global__ void podcritic_prep(const float* __restrict__ W1, const float* __restrict__ W2,
                               const float* __restrict__ Wih, const float* __restrict__ Whh,
                               short8* __restrict__ img)
{
    const int W = blockIdx.x * 4 + (threadIdx.x >> 6);   // 0..191
    const int l = threadIdx.x & 63;
    const int q = l >> 4, m = l & 15;
    FragU u;
    #pragma unroll
    for (int j = 0; j < 8; ++j) {
        float v;
        if (W < 32)       { int nt = W >> 1,        kk = W & 1;        int k = kk*32 + q*8 + j;
                            v = (k < 47) ? W1[k*256 + nt*16 + m] : 0.f; }
        else if (W < 96)  { int f = W - 32, nt = f >> 3, kk = f & 7;   int k = kk*32 + q*8 + j;
                            v = W2[k*128 + nt*16 + m]; }
        else if (W < 160) { int f = W - 96, nt = f >> 2, kk = f & 3;   int k = kk*32 + q*8 + j;
                            v = Wih[k*256 + nt*16 + m]; }
        else              { int f = W - 160, nt = f >> 1, kk = f & 1;  int k = kk*32 + q*8 + j;
                            v = Whh[k*256 + nt*16 + m]; }
        u.u[j] = f2bf(v);
    }
    img[W * 64 + l] = u.v;
}

// ============================================================================
// Encoder v3: M=32 rows (2 steps x 16 batch) per block; LDS 25.6 KB ->
// 6 blocks/CU. 3 barriers per block. wx layout unchanged (MFMA C order).
// ============================================================================
__global__ __launch_bounds__(NT, 6)
void podcritic_enc3(const float* __restrict__ self_obs,
                    const float* __restrict__ tm_obs,
                    const float* __restrict__ en_obs,
                    const float* __restrict__ cp_obs,
                    const float* __restrict__ b1, const float* __restrict__ b2,
                    const float* __restrict__ bih, const float* __restrict__ bhh,
                    const short8* __restrict__ img,
                    uint_t* __restrict__ wx, int c0)
{
    __shared__ __align__(16) ushort_t sh1[32 * SH1_STR];   // 16.9 KB
    __shared__ __align__(16) ushort_t sxe[32 * SEMB_STR];  // 8.7 KB (sx then semb)

    const int t = threadIdx.x;
    const int w = t >> 6, l = t & 63, q = l >> 4, m = l & 15;
    const int bg = blockIdx.x, b0 = bg * NB;
    const int sbase = c0 + blockIdx.y * 2;

    // gather x: 32 rows = (step mt 0..1) x (batch r 0..15)
    {
        const int col = t & 63, rw0 = t >> 6;
        #pragma unroll
        for (int jj = 0; jj < 8; ++jj) {
            int rr = 4 * jj + rw0;
            int mt = rr >> 4, r = rr & 15;
            int bs = (b0 + r) * SS + sbase + mt;
            float v = 0.f;
            if (col < 15)      v = self_obs[bs * 15 + col];
            else if (col < 28) v = tm_obs[bs * 13 + (col - 15)];
            else if (col < 41) { int k2 = col - 28;
                                 v = 0.5f * (en_obs[(bs * 2) * 13 + k2] + en_obs[(bs * 2) * 13 + 13 + k2]); }
            else if (col < 47) v = cp_obs[bs * 6 + (col - 41)];
            sxe[rr * SX_STR + col] = f2bf(v);
        }
    }
    float bias1[4], bias2[2], bgf[4];
    #pragma unroll
    for (int i = 0; i < 4; ++i) bias1[i] = b1[w * 64 + i * 16 + m];
    #pragma unroll
    for (int i = 0; i < 2; ++i) bias2[i] = b2[32 * w + 16 * i + m];
    #pragma unroll
    for (int i = 0; i < 4; ++i) { int n = (w + 4 * i) * 16 + m; bgf[i] = bih[n] + bhh[n]; }
    __syncthreads();

    // ---- phase 1: H1 = relu(x @ W1 + b1), M=32 ----
    {
        short8 w1f[4][2];
        #pragma unroll
        for (int i = 0; i < 4; ++i)
            #pragma unroll
            for (int kk = 0; kk < 2; ++kk)
                w1f[i][kk] = img[(((4 * w + i) * 2) + kk) * 64 + l];
        f32x4 c1[2][4];
        #pragma unroll
        for (int mt = 0; mt < 2; ++mt)
            #pragma unroll
            for (int i = 0; i < 4; ++i) c1[mt][i] = (f32x4){0.f, 0.f, 0.f, 0.f};
        #pragma unroll
        for (int kk = 0; kk < 2; ++kk) {
            #pragma unroll
            for (int mt = 0; mt < 2; ++mt) {
                short8 a = *(const short8*)&sxe[(mt * 16 + m) * SX_STR + kk * 32 + q * 8];
                #pragma unroll
                for (int i = 0; i < 4; ++i)
                    c1[mt][i] = __builtin_amdgcn_mfma_f32_16x16x32_bf16(a, w1f[i][kk], c1[mt][i], 0, 0, 0);
            }
        }
        #pragma unroll
        for (int mt = 0; mt < 2; ++mt)
            #pragma unroll
            for (int i = 0; i < 4; ++i) {
                int col = w * 64 + i * 16 + m;
                #pragma unroll
                for (int r = 0; r < 4; ++r)
                    sh1[(mt * 16 + q * 4 + r) * SH1_STR + col] = f2bf(fmaxf(c1[mt][i][r] + bias1[i], 0.f));
            }
    }
    __syncthreads();

    // ---- phase 2: EMB = relu(H1 @ W2 + b2) ----
    {
        short8 w2f[2][8];
        #pragma unroll
        for (int i = 0; i < 2; ++i)
            #pragma unroll
            for (int kk = 0; kk < 8; ++kk)
                w2f[i][kk] = img[(32 + ((2 * w + i) * 8) + kk) * 64 + l];
        f32x4 c2[2][2];
        #pragma unroll
        for (int mt = 0; mt < 2; ++mt)
            #pragma unroll
            for (int i = 0; i < 2; ++i) c2[mt][i] = (f32x4){0.f, 0.f, 0.f, 0.f};
        #pragma unroll
        for (int kk = 0; kk < 8; ++kk) {
            #pragma unroll
            for (int mt = 0; mt < 2; ++mt) {
                short8 a = *(const short8*)&sh1[(mt * 16 + m) * SH1_STR + kk * 32 + q * 8];
                #pragma unroll
                for (int i = 0; i < 2; ++i)
                    c2[mt][i] = __builtin_amdgcn_mfma_f32_16x16x32_bf16(a, w2f[i][kk], c2[mt][i], 0, 0, 0);
            }
        }
        #pragma unroll
        for (int mt = 0; mt < 2; ++mt)
            #pragma unroll
            for (int i = 0; i < 2; ++i) {
                int col = 32 * w + 16 * i + m;
                #pragma unroll
                for (int r = 0; r < 4; ++r)
                    sxe[(mt * 16 + q * 4 + r) * SEMB_STR + col] = f2bf(fmaxf(c2[mt][i][r] + bias2[i], 0.f));
            }
    }
    __syncthreads();

    // ---- phase 3: wx = emb @ Wih + (bih+bhh), swizzled store ----
    {
        short8 wihf[4][4];
        #pragma unroll
        for (int i = 0; i < 4; ++i)
            #pragma unroll
            for (int kk = 0; kk < 4; ++kk)
                wihf[i][kk] = img[(96 + ((w + 4 * i) * 4) + kk) * 64 + l];
        #pragma unroll
        for (int mt = 0; mt < 2; ++mt) {
            f32x4 g[4];
            #pragma unroll
            for (int i = 0; i < 4; ++i) g[i] = (f32x4){bgf[i], bgf[i], bgf[i], bgf[i]};
            #pragma unroll
            for (int kk = 0; kk < 4; ++kk) {
                short8 a = *(const short8*)&sxe[(mt * 16 + m) * SEMB_STR + kk * 32 + q * 8];
                #pragma unroll
                for (int i = 0; i < 4; ++i)
                    g[i] = __builtin_amdgcn_mfma_f32_16x16x32_bf16(a, wihf[i][kk], g[i], 0, 0, 0);
            }
            int slc = blockIdx.y * 2 + mt;
            uint_t* dst = wx + (size_t)(slc * 256 + bg) * 2048 + l * 2;
            #pragma unroll
            for (int i = 0; i < 4; ++i) {
                uint2 vv;
                vv.x = pack2(g[i][0], g[i][1]);
                vv.y = pack2(g[i][2], g[i][3]);
                *(uint2*)(dst + (w + 4 * i) * 128) = vv;
            }
        }
    }
}

// ============================================================================
// Recurrence v4: rec3 minus the val branch. h stored per step (bf16) to hseq;
// val computed later by podcritic_val. lgkm-only barrier, 2-deep prefetch.
// ============================================================================
__global__ __launch_bounds__(NT, 1)
void podcritic_rec4(const short8* __restrict__ whhimg,
                    const uint_t* __restrict__ wx,
                    ushort_t* __restrict__ hws, float* __restrict__ cws,
                    ushort_t* __restrict__ hseq,
                    float* __restrict__ out, int first, int last)
{
    __shared__ __align__(16) ushort_t sh[2][NB * SH_STR];

    const int t  = threadIdx.x;
    const int w  = t >> 6, l = t & 63, q = l >> 4, m = l & 15;
    const int bg = blockIdx.x, b0 = bg * NB;

    short8 whhf[4][2];
    #pragma unroll
    for (int a = 0; a < 4; ++a)
        #pragma unroll
        for (int kk = 0; kk < 2; ++kk)
            whhf[a][kk] = whhimg[(((w + 4 * a) * 2) + kk) * 64 + l];

    float creg[4], hlast[4] = {0.f, 0.f, 0.f, 0.f};
    if (first) {
        #pragma unroll
        for (int r = 0; r < 4; ++r) creg[r] = 0.f;
        int idx4 = t * 4, row = idx4 >> 6, col = idx4 & 63;
        uint2 z; z.x = 0u; z.y = 0u;
        *(uint2*)&sh[0][row * SH_STR + col] = z;
    } else {
        int idx4 = t * 4, row = idx4 >> 6, col = idx4 & 63;
        uint2 hv2 = *(const uint2*)((const uint_t*)(hws + (size_t)bg * 1024 + idx4));
        *(uint2*)&sh[0][row * SH_STR + col] = hv2;
        float4 cv = *(const float4*)(cws + ((size_t)bg * 256 + t) * 4);
        creg[0] = cv.x; creg[1] = cv.y; creg[2] = cv.z; creg[3] = cv.w;
    }

    // 2-deep wx prefetch ring
    uint2 upf[2][4];
    {
        const uint_t* p0 = wx + (size_t)(0 * 256 + bg) * 2048 + l * 2;
        const uint_t* p1 = wx + (size_t)(1 * 256 + bg) * 2048 + l * 2;
        #pragma unroll
        for (int a = 0; a < 4; ++a) {
            upf[0][a] = *(const uint2*)(p0 + (w + 4 * a) * 128);
            upf[1][a] = *(const uint2*)(p1 + (w + 4 * a) * 128);
        }
    }
    // h-seq store base for this lane: rows b0+q*4+r, hidden 16w+m
    ushort_t* hsp = hseq + (size_t)(b0 + q * 4) * 64 + 16 * w + m;
    const size_t hstep = (size_t)BB * 64;

    barrier_lgkm();

    #pragma unroll 2
    for (int sl = 0; sl < CS; ++sl) {
        const int par = sl & 1;

        short8 af0 = *(const short8*)&sh[par][m * SH_STR + q * 8];
        short8 af1 = *(const short8*)&sh[par][m * SH_STR + 32 + q * 8];

        f32x4 g[4];
        #pragma unroll
        for (int a = 0; a < 4; ++a) {
            g[a][0] = bflo(upf[par][a].x); g[a][1] = bfhi(upf[par][a].x);
            g[a][2] = bflo(upf[par][a].y); g[a][3] = bfhi(upf[par][a].y);
        }

        {
            int snext = (sl + 2 < CS) ? (sl + 2) : sl;
            const uint_t* pn = wx + (size_t)(snext * 256 + bg) * 2048 + l * 2;
            #pragma unroll
            for (int a = 0; a < 4; ++a)
                upf[par][a] = *(const uint2*)(pn + (w + 4 * a) * 128);
        }

        #pragma unroll
        for (int a = 0; a < 4; ++a) {
            g[a] = __builtin_amdgcn_mfma_f32_16x16x32_bf16(af0, whhf[a][0], g[a], 0, 0, 0);
            g[a] = __builtin_amdgcn_mfma_f32_16x16x32_bf16(af1, whhf[a][1], g[a], 0, 0, 0);
        }

        #pragma unroll
        for (int r = 0; r < 4; ++r) {
            float gi = fsig(g[0][r]);
            float gf = fsig(g[1][r]);
            float gg = ftanh(g[2][r]);
            float go = fsig(g[3][r]);
            float c  = gf * creg[r] + gi * gg;
            creg[r] = c;
            float h = go * ftanh(c);
            hlast[r] = h;
            ushort_t hb = f2bf(h);
            sh[par ^ 1][(q * 4 + r) * SH_STR + 16 * w + m] = hb;
            hsp[(size_t)sl * hstep + r * 64] = hb;   // global, non-blocking
        }

        barrier_lgkm();
    }

    if (!last) {
        const int jcol = 16 * w + m;
        #pragma unroll
        for (int r = 0; r < 4; ++r)
            hws[(size_t)bg * 1024 + (q * 4 + r) * 64 + jcol] = f2bf(hlast[r]);
        float4 cv; cv.x = creg[0]; cv.y = creg[1]; cv.z = creg[2]; cv.w = creg[3];
        *(float4*)(cws + ((size_t)bg * 256 + t) * 4) = cv;
    } else {
        const int jcol = 16 * w + m;
        #pragma unroll
        for (int r = 0; r < 4; ++r) {
            int row = b0 + q * 4 + r;
            out[BB * SS + (size_t)row * 64 + jcol]           = hlast[r];
            out[BB * SS + BB * 64 + (size_t)row * 64 + jcol] = creg[r];
        }
    }
}

// ============================================================================
// Deferred value head: out[b, c0+sl] = hseq[sl, b, :] . Wv + bv.
// 16 lanes per row, uint2 loads, 4-round shfl reduce. Grid 512 x 256.
// ============================================================================
__global__ __launch_bounds__(NT)
void podcritic_val(const ushort_t* __restrict__ hseq,
                   const float* __restrict__ Wv, const float* __restrict__ bv,
                   float* __restrict__ out, int c0)
{
    const int t = threadIdx.x;
    const int lane16 = t & 15;
    const int row = blockIdx.x * 16 + (t >> 4);       // [0, 131072)
    float4 wv = *(const float4*)(Wv + lane16 * 4);
    uint2 hv = *(const uint2*)(hseq + (size_t)row * 64 + lane16 * 4);
    float pv = bflo(hv.x) * wv.x + bfhi(hv.x) * wv.y
             + bflo(hv.y) * wv.z + bfhi(hv.y) * wv.w;
    pv += __shfl_xor(pv, 1, 64);
    pv += __shfl_xor(pv, 2, 64);
    pv += __shfl_xor(pv, 4, 64);
    pv += __shfl_xor(pv, 8, 64);
    if (lane16 == 0) {
        int sl = row >> 12, b = row & 4095;
        out[(size_t)b * SS + c0 + sl] = pv + bv[0];
    }
}

// ============================================================================
// Recurrence v3 (mid-tier: val in-loop, no hseq) — unchanged from round 5.
// ============================================================================
__global__ __launch_bounds__(NT, 1)
void podcritic_rec3(const short8* __restrict__ whhimg,
                    const float* __restrict__ Wv, const float* __restrict__ bv,
                    const uint_t* __restrict__ wx,
                    ushort_t* __restrict__ hws, float* __restrict__ cws,
                    float* __restrict__ out, int c0, int first, int last)
{
    __shared__ __align__(16) ushort_t sh[2][NB * SH_STR];
    __shared__ float sval[2][64];

    const int t  = threadIdx.x;
    const int w  = t >> 6, l = t & 63, q = l >> 4, m = l & 15;
    const int bg = blockIdx.x, b0 = bg * NB;

    short8 whhf[4][2];
    #pragma unroll
    for (int a = 0; a < 4; ++a)
        #pragma unroll
        for (int kk = 0; kk < 2; ++kk)
            whhf[a][kk] = whhimg[(((w + 4 * a) * 2) + kk) * 64 + l];

    const float wv  = Wv[16 * w + m];
    const float bvv = bv[0];

    float creg[4], hlast[4] = {0.f, 0.f, 0.f, 0.f};
    if (first) {
        #pragma unroll
        for (int r = 0; r < 4; ++r) creg[r] = 0.f;
        int idx4 = t * 4, row = idx4 >> 6, col = idx4 & 63;
        uint2 z; z.x = 0u; z.y = 0u;
        *(uint2*)&sh[0][row * SH_STR + col] = z;
    } else {
        int idx4 = t * 4, row = idx4 >> 6, col = idx4 & 63;
        uint2 hv2 = *(const uint2*)((const uint_t*)(hws + (size_t)bg * 1024 + idx4));
        *(uint2*)&sh[0][row * SH_STR + col] = hv2;
        float4 cv = *(const float4*)(cws + ((size_t)bg * 256 + t) * 4);
        creg[0] = cv.x; creg[1] = cv.y; creg[2] = cv.z; creg[3] = cv.w;
    }

    uint2 upf[2][4];
    {
        const uint_t* p0 = wx + (size_t)(0 * 256 + bg) * 2048 + l * 2;
        const uint_t* p1 = wx + (size_t)(1 * 256 + bg) * 2048 + l * 2;
        #pragma unroll
        for (int a = 0; a < 4; ++a) {
            upf[0][a] = *(const uint2*)(p0 + (w + 4 * a) * 128);
            upf[1][a] = *(const uint2*)(p1 + (w + 4 * a) * 128);
        }
    }
    barrier_lgkm();

    #pragma unroll 2
    for (int sl = 0; sl < CS; ++sl) {
        const int par = sl & 1;

        short8 af0 = *(const short8*)&sh[par][m * SH_STR + q * 8];
        short8 af1 = *(const short8*)&sh[par][m * SH_STR + 32 + q * 8];

        f32x4 g[4];
        #pragma unroll
        for (int a = 0; a < 4; ++a) {
            g[a][0] = bflo(upf[par][a].x); g[a][1] = bfhi(upf[par][a].x);
            g[a][2] = bflo(upf[par][a].y); g[a][3] = bfhi(upf[par][a].y);
        }

        {
            int snext = (sl + 2 < CS) ? (sl + 2) : sl;
            const uint_t* pn = wx + (size_t)(snext * 256 + bg) * 2048 + l * 2;
            #pragma unroll
            for (int a = 0; a < 4; ++a)
                upf[par][a] = *(const uint2*)(pn + (w + 4 * a) * 128);
        }

        #pragma unroll
        for (int a = 0; a < 4; ++a) {
            g[a] = __builtin_amdgcn_mfma_f32_16x16x32_bf16(af0, whhf[a][0], g[a], 0, 0, 0);
            g[a] = __builtin_amdgcn_mfma_f32_16x16x32_bf16(af1, whhf[a][1], g[a], 0, 0, 0);
        }

        float pv[4];
        #pragma unroll
        for (int r = 0; r < 4; ++r) {
            float gi = fsig(g[0][r]);
            float gf = fsig(g[1][r]);
            float gg = ftanh(g[2][r]);
            float go = fsig(g[3][r]);
            float c  = gf * creg[r] + gi * gg;
            creg[r] = c;
            float h = go * ftanh(c);
            hlast[r] = h;
            sh[par ^ 1][(q * 4 + r) * SH_STR + 16 * w + m] = f2bf(h);
            pv[r] = h * wv;
        }
        #pragma unroll
        for (int mask = 1; mask <= 8; mask <<= 1) {
            #pragma unroll
            for (int r = 0; r < 4; ++r) pv[r] += __shfl_xor(pv[r], mask, 64);
        }
        if (m == 0) {
            #pragma unroll
            for (int r = 0; r < 4; ++r) sval[par][w * 16 + 4 * q + r] = pv[r];
        }

        barrier_lgkm();

        if (t < 16)
            out[(size_t)(b0 + t) * SS + (c0 + sl)] =
                sval[par][t] + sval[par][16 + t] + sval[par][32 + t] + sval[par][48 + t] + bvv;
    }

    if (!last) {
        const int jcol = 16 * w + m;
        #pragma unroll
        for (int r = 0; r < 4; ++r)
            hws[(size_t)bg * 1024 + (q * 4 + r) * 64 + jcol] = f2bf(hlast[r]);
        float4 cv; cv.x = creg[0]; cv.y = creg[1]; cv.z = creg[2]; cv.w = creg[3];
        *(float4*)(cws + ((size_t)bg * 256 + t) * 4) = cv;
    } else {
        const int jcol = 16 * w + m;
        #pragma unroll
        for (int r = 0; r < 4; ++r) {
            int row = b0 + q * 4 + r;
            out[BB * SS + (size_t)row * 64 + jcol]           = hlast[r];
            out[BB * SS + BB * 64 + (size_t)row * 64 + jcol] = creg[r];
        }
    }
}

// ============================================================================
// Fallback: round-2 fused kernel (only if ws is tiny)
// ============================================================================
__global__ __launch_bounds__(NT, 1)
void podcritic_mfma(const float* __restrict__ self_obs,
                    const float* __restrict__ tm_obs,
                    const float* __restrict__ en_obs,
                    const float* __restrict__ cp_obs,
                    const float* __restrict__ W1, const float* __restrict__ b1,
                    const float* __restrict__ W2, const float* __restrict__ b2,
                    const float* __restrict__ Wih, const float* __restrict__ bih,
                    const float* __restrict__ Whh, const float* __restrict__ bhh,
                    const float* __restrict__ Wv, const float* __restrict__ bv,
                    float* __restrict__ out)
{
    __shared__ __align__(16) ushort_t sx[2][NB * SX_STR];
    __shared__ __align__(16) ushort_t sh1[NB * SH1_STR];
    __shared__ __align__(16) ushort_t semb[NB * SEMB_STR];
    __shared__ __align__(16) ushort_t sh[NB * SH_STR];
    __shared__ float sWv[64];

    const int t  = threadIdx.x;
    const int w  = t >> 6;
    const int l  = t & 63;
    const int q  = l >> 4;
    const int m  = l & 15;
    const int b0 = blockIdx.x * NB;

    short8 w1f[4][2];
    short8 w2f[2][8];
    short8 wihf[4][4];
    short8 whhf[4][2];
    float bias1[4], bias2[2], bg[4];

    #pragma unroll
    for (int i = 0; i < 4; ++i) {
        int n = w * 64 + i * 16 + m;
        bias1[i] = b1[n];
        #pragma unroll
        for (int kk = 0; kk < 2; ++kk) {
            FragU u;
            #pragma unroll
            for (int j = 0; j < 8; ++j) {
                int k = kk * 32 + q * 8 + j;
                u.u[j] = f2bf(k < 47 ? W1[k * 256 + n] : 0.f);
            }
            w1f[i][kk] = u.v;
        }
    }
    #pragma unroll
    for (int i = 0; i < 2; ++i) {
        int n = 32 * w + i * 16 + m;
        bias2[i] = b2[n];
        #pragma unroll
        for (int kk = 0; kk < 8; ++kk) {
            FragU u;
            #pragma unroll
            for (int j = 0; j < 8; ++j) {
                int k = kk * 32 + q * 8 + j;
                u.u[j] = f2bf(W2[k * 128 + n]);
            }
            w2f[i][kk] = u.v;
        }
    }
    #pragma unroll
    for (int i = 0; i < 4; ++i) {
        int n = (w + 4 * i) * 16 + m;
        bg[i] = bih[n] + bhh[n];
        #pragma unroll
        for (int kk = 0; kk < 4; ++kk) {
            FragU u;
            #pragma unroll
            for (int j = 0; j < 8; ++j) {
                int k = kk * 32 + q * 8 + j;
                u.u[j] = f2bf(Wih[k * 256 + n]);
            }
            wihf[i][kk] = u.v;
        }
        #pragma unroll
        for (int kk = 0; kk < 2; ++kk) {
            FragU u;
            #pragma unroll
            for (int j = 0; j < 8; ++j) {
                int k = kk * 32 + q * 8 + j;
                u.u[j] = f2bf(Whh[k * 256 + n]);
            }
            whhf[i][kk] = u.v;
        }
    }
    const float bvv = bv[0];
    if (t < 64) sWv[t] = Wv[t];

    for (int idx = t; idx < NB * SH_STR; idx += NT) sh[idx] = 0;

    const int pcol = t & 63;
    const int prow = t >> 6;
    #pragma unroll
    for (int j = 0; j < 4; ++j) {
        int r  = 4 * j + prow;
        int bs = (b0 + r) * SS + 0;
        float v = 0.f;
        if (pcol < 15)      v = self_obs[bs * 15 + pcol];
        else if (pcol < 28) v = tm_obs[bs * 13 + (pcol - 15)];
        else if (pcol < 41) { int kk = pcol - 28;
                              v = 0.5f * (en_obs[(bs * 2) * 13 + kk] + en_obs[(bs * 2) * 13 + 13 + kk]); }
        else if (pcol < 47) v = cp_obs[bs * 6 + (pcol - 41)];
        sx[0][r * SX_STR + pcol] = f2bf(v);
    }
    __syncthreads();

    float creg[4] = {0.f, 0.f, 0.f, 0.f};
    float hreg[4] = {0.f, 0.f, 0.f, 0.f};
    int cur = 0;

    for (int s = 0; s < SS; ++s) {
        float pf[4];
        #pragma unroll
        for (int j = 0; j < 4; ++j) {
            float v = 0.f;
            if (s + 1 < SS) {
                int r  = 4 * j + prow;
                int bs = (b0 + r) * SS + (s + 1);
                if (pcol < 15)      v = self_obs[bs * 15 + pcol];
                else if (pcol < 28) v = tm_obs[bs * 13 + (pcol - 15)];
                else if (pcol < 41) { int kk = pcol - 28;
                                      v = 0.5f * (en_obs[(bs * 2) * 13 + kk] + en_obs[(bs * 2) * 13 + 13 + kk]); }
                else if (pcol < 47) v = cp_obs[bs * 6 + (pcol - 41)];
            }
            pf[j] = v;
        }

        {
            f32x4 c1[4] = {{0,0,0,0},{0,0,0,0},{0,0,0,0},{0,0,0,0}};
            #pragma unroll
            for (int kk = 0; kk < 2; ++kk) {
                short8 a = *(const short8*)&sx[cur][m * SX_STR + kk * 32 + q * 8];
                #pragma unroll
                for (int i = 0; i < 4; ++i)
                    c1[i] = __builtin_amdgcn_mfma_f32_16x16x32_bf16(a, w1f[i][kk], c1[i], 0, 0, 0);
            }
            #pragma unroll
            for (int i = 0; i < 4; ++i) {
                int col = w * 64 + i * 16 + m;
                #pragma unroll
                for (int r = 0; r < 4; ++r)
                    sh1[(q * 4 + r) * SH1_STR + col] = f2bf(fmaxf(c1[i][r] + bias1[i], 0.f));
            }
        }
        __syncthreads();

        {
            f32x4 c2[2] = {{0,0,0,0},{0,0,0,0}};
            #pragma unroll
            for (int kk = 0; kk < 8; ++kk) {
                short8 a = *(const short8*)&sh1[m * SH1_STR + kk * 32 + q * 8];
                #pragma unroll
                for (int i = 0; i < 2; ++i)
                    c2[i] = __builtin_amdgcn_mfma_f32_16x16x32_bf16(a, w2f[i][kk], c2[i], 0, 0, 0);
            }
            #pragma unroll
            for (int i = 0; i < 2; ++i) {
                int col = 32 * w + i * 16 + m;
                #pragma unroll
                for (int r = 0; r < 4; ++r)
                    semb[(q * 4 + r) * SEMB_STR + col] = f2bf(fmaxf(c2[i][r] + bias2[i], 0.f));
            }
        }
        __syncthreads();

        {
            f32x4 g[4];
            #pragma unroll
            for (int i = 0; i < 4; ++i) g[i] = (f32x4){bg[i], bg[i], bg[i], bg[i]};
            #pragma unroll
            for (int kk = 0; kk < 4; ++kk) {
                short8 a = *(const short8*)&semb[m * SEMB_STR + kk * 32 + q * 8];
                #pragma unroll
                for (int i = 0; i < 4; ++i)
                    g[i] = __builtin_amdgcn_mfma_f32_16x16x32_bf16(a, wihf[i][kk], g[i], 0, 0, 0);
            }
            #pragma unroll
            for (int kk = 0; kk < 2; ++kk) {
                short8 a = *(const short8*)&sh[m * SH_STR + kk * 32 + q * 8];
                #pragma unroll
                for (int i = 0; i < 4; ++i)
                    g[i] = __builtin_amdgcn_mfma_f32_16x16x32_bf16(a, whhf[i][kk], g[i], 0, 0, 0);
            }
            const int jcol = 16 * w + m;
            #pragma unroll
            for (int r = 0; r < 4; ++r) {
                float gi = fsig(g[0][r]);
                float gf = fsig(g[1][r]);
                float gg = ftanh(g[2][r]);
                float go = fsig(g[3][r]);
                float c  = gf * creg[r] + gi * gg;
                creg[r] = c;
                float h = go * ftanh(c);
                hreg[r] = h;
                sh[(q * 4 + r) * SH_STR + jcol] = f2bf(h);
            }
            #pragma unroll
            for (int j = 0; j < 4; ++j) {
                int r = 4 * j + prow;
                sx[cur ^ 1][r * SX_STR + pcol] = f2bf(pf[j]);
            }
        }
        __syncthreads();

        {
            int r = t >> 4, pp = t & 15;
            const ushort_t* hp = &sh[r * SH_STR + pp * 4];
            float pv = 0.f;
            #pragma unroll
            for (int j = 0; j < 4; ++j) pv += bf2f(hp[j]) * sWv[pp * 4 + j];
            pv += __shfl_xor(pv, 1, 16);
            pv += __shfl_xor(pv, 2, 16);
            pv += __shfl_xor(pv, 4, 16);
            pv += __shfl_xor(pv, 8, 16);
            if (pp == 0) out[(b0 + r) * SS + s] = pv + bvv;
        }
        cur ^= 1;
    }

    {
        const int jcol = 16 * w + m;
        #pragma unroll
        for (int r = 0; r < 4; ++r) {
            int row = b0 + q * 4 + r;
            out[BB * SS + row * 64 + jcol]           = hreg[r];
            out[BB * SS + BB * 64 + row * 64 + jcol] = creg[r];
        }
    }
}

extern "C" void kernel_launch(void* const* d_in, const int* in_sizes, int n_in,
                              void* d_out, int out_size, void* d_ws, size_t ws_size,
                              hipStream_t stream) {
    const float* self_obs = (const float*)d_in[0];
    const float* tm_obs   = (const float*)d_in[1];
    const float* en_obs   = (const float*)d_in[2];
    const float* cp_obs   = (const float*)d_in[3];
    const float* W1  = (const float*)d_in[4];
    const float* b1  = (const float*)d_in[5];
    const float* W2  = (const float*)d_in[6];
    const float* b2  = (const float*)d_in[7];
    const float* Wih = (const float*)d_in[8];
    const float* bih = (const float*)d_in[9];
    const float* Whh = (const float*)d_in[10];
    const float* bhh = (const float*)d_in[11];
    const float* Wv  = (const float*)d_in[12];
    const float* bv  = (const float*)d_in[13];
    float* out = (float*)d_out;

    const size_t wx_bytes   = (size_t)CS * 256 * 2048 * 4;   // 67,108,864
    const size_t h_bytes    = 256 * 1024 * 2;                // 524,288
    const size_t c_bytes    = 256 * 1024 * 4;                // 1,048,576
    const size_t img_bytes  = 192 * 64 * 16;                 // 196,608
    const size_t hseq_bytes = (size_t)CS * BB * 64 * 2;      // 16,777,216
    const size_t need1      = wx_bytes + h_bytes + c_bytes + img_bytes;
    const size_t need2      = need1 + hseq_bytes;

    if (ws_size >= need1) {
        uint_t*   wx  = (uint_t*)d_ws;
        ushort_t* hws = (ushort_t*)((char*)d_ws + wx_bytes);
        float*    cws = (float*)((char*)d_ws + wx_bytes + h_bytes);
        short8*   img = (short8*)((char*)d_ws + wx_bytes + h_bytes + c_bytes);
        const short8* whhimg = img + 160 * 64;

        podcritic_prep<<<48, NT, 0, stream>>>(W1, W2, Wih, Whh, img);
        if (ws_size >= need2) {
            ushort_t* hseq = (ushort_t*)((char*)d_ws + need1);
            for (int c = 0; c < NCH; ++c) {
                podcritic_enc3<<<dim3(256, CS / 2), NT, 0, stream>>>(
                    self_obs, tm_obs, en_obs, cp_obs,
                    b1, b2, bih, bhh, img, wx, c * CS);
                podcritic_rec4<<<256, NT, 0, stream>>>(
                    whhimg, wx, hws, cws, hseq, out,
                    (c == 0) ? 1 : 0, (c == NCH - 1) ? 1 : 0);
                podcritic_val<<<CS * BB / 16, NT, 0, stream>>>(
                    hseq, Wv, bv, out, c * CS);
            }
        } else {
            for (int c = 0; c < NCH; ++c) {
                podcritic_enc3<<<dim3(256, CS / 2), NT, 0, stream>>>(
                    self_obs, tm_obs, en_obs, cp_obs,
                    b1, b2, bih, bhh, img, wx, c * CS);
                podcritic_rec3<<<256, NT, 0, stream>>>(
                    whhimg, Wv, bv, wx, hws, cws, out, c * CS,
                    (c == 0) ? 1 : 0, (c == NCH - 1) ? 1 : 0);
            }
        }
    } else {
        podcritic_mfma<<<BB / NB, NT, 0, stream>>>(
            self_obs, tm_obs, en_obs, cp_obs,
            W1, b1, W2, b2, Wih, bih, Whh, bhh, Wv, bv, out);
    }
}

// Round 7
// 532.755 us; speedup vs baseline: 1.6986x; 1.1358x over previous
//
#include <hip/hip_runtime.h>

#define BB 4096
#define SS 128
#define NB 16
#define NT 256
#define CS 16          // timesteps per chunk
#define NCH (SS/CS)    // 8 chunks

typedef __attribute__((ext_vector_type(8))) short short8;
typedef __attribute__((ext_vector_type(4))) float f32x4;
typedef unsigned short ushort_t;
typedef unsigned int uint_t;

#define SX_STR   72
#define SH1_STR  264
#define SEMB_STR 136
#define SH_STR   72
#define ENC_LDS_USHORTS (32 * SH1_STR + 32 * SEMB_STR)   // 12800 -> 25.6 KB

__device__ __forceinline__ ushort_t f2bf(float f) {
    union { float f; unsigned u; } x; x.f = f;
    unsigned r = x.u + 0x7FFFu + ((x.u >> 16) & 1u);
    return (ushort_t)(r >> 16);
}
__device__ __forceinline__ uint_t pack2(float a, float b) {
    return (uint_t)f2bf(a) | ((uint_t)f2bf(b) << 16);
}
__device__ __forceinline__ float bflo(uint_t u) {
    union { unsigned u; float f; } x; x.u = u << 16; return x.f;
}
__device__ __forceinline__ float bfhi(uint_t u) {
    union { unsigned u; float f; } x; x.u = u & 0xFFFF0000u; return x.f;
}
__device__ __forceinline__ float bf2f(ushort_t h) {
    union { unsigned u; float f; } x; x.u = ((unsigned)h) << 16; return x.f;
}
// FAST pointwise: v_rcp_f32 instead of the precise-div sequence (the precise
// divide was ~15 dependent VALU ops on the recurrence critical path).
__device__ __forceinline__ float fsig(float x) {
    return __builtin_amdgcn_rcpf(1.f + __expf(-x));
}
__device__ __forceinline__ float ftanh(float x) {
    return 1.f - 2.f * __builtin_amdgcn_rcpf(__expf(2.f * x) + 1.f);
}
// workgroup barrier WITHOUT vmcnt drain (LDS ordering only)
__device__ __forceinline__ void barrier_lgkm() {
    asm volatile("s_waitcnt lgkmcnt(0)\n\ts_barrier" ::: "memory");
}

union FragU { short8 v; ushort_t u[8]; };

// ============================================================================
// Prep: bf16 B-fragment images for W1/W2/Wih/Whh.
// ============================================================================
__global__ void podcritic_prep(const float* __restrict__ W1, const float* __restrict__ W2,
                               const float* __restrict__ Wih, const float* __restrict__ Whh,
                               short8* __restrict__ img)
{
    const int W = blockIdx.x * 4 + (threadIdx.x >> 6);   // 0..191
    const int l = threadIdx.x & 63;
    const int q = l >> 4, m = l & 15;
    FragU u;
    #pragma unroll
    for (int j = 0; j < 8; ++j) {
        float v;
        if (W < 32)       { int nt = W >> 1,        kk = W & 1;        int k = kk*32 + q*8 + j;
                            v = (k < 47) ? W1[k*256 + nt*16 + m] : 0.f; }
        else if (W < 96)  { int f = W - 32, nt = f >> 3, kk = f & 7;   int k = kk*32 + q*8 + j;
                            v = W2[k*128 + nt*16 + m]; }
        else if (W < 160) { int f = W - 96, nt = f >> 2, kk = f & 3;   int k = kk*32 + q*8 + j;
                            v = Wih[k*256 + nt*16 + m]; }
        else              { int f = W - 160, nt = f >> 1, kk = f & 1;  int k = kk*32 + q*8 + j;
                            v = Whh[k*256 + nt*16 + m]; }
        u.u[j] = f2bf(v);
    }
    img[W * 64 + l] = u.v;
}

// ============================================================================
// Encoder block (device fn): M=32 rows (2 steps x 16 batch), 3 lgkm barriers.
// ============================================================================
__device__ __forceinline__ void enc_block(
    ushort_t* smem,
    const float* __restrict__ self_obs, const float* __restrict__ tm_obs,
    const float* __restrict__ en_obs,   const float* __restrict__ cp_obs,
    const float* __restrict__ b1, const float* __restrict__ b2,
    const float* __restrict__ bih, const float* __restrict__ bhh,
    const short8* __restrict__ img, uint_t* __restrict__ wx, int c0, int e)
{
    ushort_t* sh1 = smem;                     // 32*SH1_STR
    ushort_t* sxe = smem + 32 * SH1_STR;      // 32*SEMB_STR (x then emb)

    const int t = threadIdx.x;
    const int w = t >> 6, l = t & 63, q = l >> 4, m = l & 15;
    const int bg = e & 255, b0 = bg * NB;
    const int ytile = e >> 8;                 // 0..7
    const int sbase = c0 + ytile * 2;

    // gather x: 32 rows = (step mt 0..1) x (batch r 0..15)
    {
        const int col = t & 63, rw0 = t >> 6;
        #pragma unroll
        for (int jj = 0; jj < 8; ++jj) {
            int rr = 4 * jj + rw0;
            int mt = rr >> 4, r = rr & 15;
            int bs = (b0 + r) * SS + sbase + mt;
            float v = 0.f;
            if (col < 15)      v = self_obs[bs * 15 + col];
            else if (col < 28) v = tm_obs[bs * 13 + (col - 15)];
            else if (col < 41) { int k2 = col - 28;
                                 v = 0.5f * (en_obs[(bs * 2) * 13 + k2] + en_obs[(bs * 2) * 13 + 13 + k2]); }
            else if (col < 47) v = cp_obs[bs * 6 + (col - 41)];
            sxe[rr * SX_STR + col] = f2bf(v);
        }
    }
    float bias1[4], bias2[2], bgf[4];
    #pragma unroll
    for (int i = 0; i < 4; ++i) bias1[i] = b1[w * 64 + i * 16 + m];
    #pragma unroll
    for (int i = 0; i < 2; ++i) bias2[i] = b2[32 * w + 16 * i + m];
    #pragma unroll
    for (int i = 0; i < 4; ++i) { int n = (w + 4 * i) * 16 + m; bgf[i] = bih[n] + bhh[n]; }
    barrier_lgkm();

    // ---- phase 1: H1 = relu(x @ W1 + b1), M=32 ----
    {
        short8 w1f[4][2];
        #pragma unroll
        for (int i = 0; i < 4; ++i)
            #pragma unroll
            for (int kk = 0; kk < 2; ++kk)
                w1f[i][kk] = img[(((4 * w + i) * 2) + kk) * 64 + l];
        f32x4 c1[2][4];
        #pragma unroll
        for (int mt = 0; mt < 2; ++mt)
            #pragma unroll
            for (int i = 0; i < 4; ++i) c1[mt][i] = (f32x4){0.f, 0.f, 0.f, 0.f};
        #pragma unroll
        for (int kk = 0; kk < 2; ++kk) {
            #pragma unroll
            for (int mt = 0; mt < 2; ++mt) {
                short8 a = *(const short8*)&sxe[(mt * 16 + m) * SX_STR + kk * 32 + q * 8];
                #pragma unroll
                for (int i = 0; i < 4; ++i)
                    c1[mt][i] = __builtin_amdgcn_mfma_f32_16x16x32_bf16(a, w1f[i][kk], c1[mt][i], 0, 0, 0);
            }
        }
        #pragma unroll
        for (int mt = 0; mt < 2; ++mt)
            #pragma unroll
            for (int i = 0; i < 4; ++i) {
                int col = w * 64 + i * 16 + m;
                #pragma unroll
                for (int r = 0; r < 4; ++r)
                    sh1[(mt * 16 + q * 4 + r) * SH1_STR + col] = f2bf(fmaxf(c1[mt][i][r] + bias1[i], 0.f));
            }
    }
    barrier_lgkm();

    // ---- phase 2: EMB = relu(H1 @ W2 + b2) ----
    {
        short8 w2f[2][8];
        #pragma unroll
        for (int i = 0; i < 2; ++i)
            #pragma unroll
            for (int kk = 0; kk < 8; ++kk)
                w2f[i][kk] = img[(32 + ((2 * w + i) * 8) + kk) * 64 + l];
        f32x4 c2[2][2];
        #pragma unroll
        for (int mt = 0; mt < 2; ++mt)
            #pragma unroll
            for (int i = 0; i < 2; ++i) c2[mt][i] = (f32x4){0.f, 0.f, 0.f, 0.f};
        #pragma unroll
        for (int kk = 0; kk < 8; ++kk) {
            #pragma unroll
            for (int mt = 0; mt < 2; ++mt) {
                short8 a = *(const short8*)&sh1[(mt * 16 + m) * SH1_STR + kk * 32 + q * 8];
                #pragma unroll
                for (int i = 0; i < 2; ++i)
                    c2[mt][i] = __builtin_amdgcn_mfma_f32_16x16x32_bf16(a, w2f[i][kk], c2[mt][i], 0, 0, 0);
            }
        }
        #pragma unroll
        for (int mt = 0; mt < 2; ++mt)
            #pragma unroll
            for (int i = 0; i < 2; ++i) {
                int col = 32 * w + 16 * i + m;
                #pragma unroll
                for (int r = 0; r < 4; ++r)
                    sxe[(mt * 16 + q * 4 + r) * SEMB_STR + col] = f2bf(fmaxf(c2[mt][i][r] + bias2[i], 0.f));
            }
    }
    barrier_lgkm();

    // ---- phase 3: wx = emb @ Wih + (bih+bhh), swizzled store ----
    {
        short8 wihf[4][4];
        #pragma unroll
        for (int i = 0; i < 4; ++i)
            #pragma unroll
            for (int kk = 0; kk < 4; ++kk)
                wihf[i][kk] = img[(96 + ((w + 4 * i) * 4) + kk) * 64 + l];
        #pragma unroll
        for (int mt = 0; mt < 2; ++mt) {
            f32x4 g[4];
            #pragma unroll
            for (int i = 0; i < 4; ++i) g[i] = (f32x4){bgf[i], bgf[i], bgf[i], bgf[i]};
            #pragma unroll
            for (int kk = 0; kk < 4; ++kk) {
                short8 a = *(const short8*)&sxe[(mt * 16 + m) * SEMB_STR + kk * 32 + q * 8];
                #pragma unroll
                for (int i = 0; i < 4; ++i)
                    g[i] = __builtin_amdgcn_mfma_f32_16x16x32_bf16(a, wihf[i][kk], g[i], 0, 0, 0);
            }
            int slc = ytile * 2 + mt;
            uint_t* dst = wx + (size_t)(slc * 256 + bg) * 2048 + l * 2;
            #pragma unroll
            for (int i = 0; i < 4; ++i) {
                uint2 vv;
                vv.x = pack2(g[i][0], g[i][1]);
                vv.y = pack2(g[i][2], g[i][3]);
                *(uint2*)(dst + (w + 4 * i) * 128) = vv;
            }
        }
    }
}

// ============================================================================
// Recurrence block (device fn): 4 waves / 16 batch rows, 1 lgkm barrier/step,
// 2-deep wx prefetch, fast pointwise, h streamed to hseq.
// ============================================================================
__device__ __forceinline__ void rec_block(
    ushort_t* smem,
    const short8* __restrict__ whhimg, const uint_t* __restrict__ wx,
    ushort_t* __restrict__ hws, float* __restrict__ cws,
    ushort_t* __restrict__ hseq, float* __restrict__ out, int first, int last)
{
    const int t = threadIdx.x;
    const int w = t >> 6, l = t & 63, q = l >> 4, m = l & 15;
    const int bg = blockIdx.x, b0 = bg * NB;

    short8 whhf[4][2];
    #pragma unroll
    for (int a = 0; a < 4; ++a)
        #pragma unroll
        for (int kk = 0; kk < 2; ++kk)
            whhf[a][kk] = whhimg[(((w + 4 * a) * 2) + kk) * 64 + l];

    float creg[4], hlast[4] = {0.f, 0.f, 0.f, 0.f};
    if (first) {
        #pragma unroll
        for (int r = 0; r < 4; ++r) creg[r] = 0.f;
        int idx4 = t * 4, row = idx4 >> 6, col = idx4 & 63;
        uint2 z; z.x = 0u; z.y = 0u;
        *(uint2*)&smem[row * SH_STR + col] = z;
    } else {
        int idx4 = t * 4, row = idx4 >> 6, col = idx4 & 63;
        uint2 hv2 = *(const uint2*)((const uint_t*)(hws + (size_t)bg * 1024 + idx4));
        *(uint2*)&smem[row * SH_STR + col] = hv2;
        float4 cv = *(const float4*)(cws + ((size_t)bg * 256 + t) * 4);
        creg[0] = cv.x; creg[1] = cv.y; creg[2] = cv.z; creg[3] = cv.w;
    }

    uint2 upf[2][4];
    {
        const uint_t* p0 = wx + (size_t)(0 * 256 + bg) * 2048 + l * 2;
        const uint_t* p1 = wx + (size_t)(1 * 256 + bg) * 2048 + l * 2;
        #pragma unroll
        for (int a = 0; a < 4; ++a) {
            upf[0][a] = *(const uint2*)(p0 + (w + 4 * a) * 128);
            upf[1][a] = *(const uint2*)(p1 + (w + 4 * a) * 128);
        }
    }
    ushort_t* hsp = hseq + (size_t)(b0 + q * 4) * 64 + 16 * w + m;
    const size_t hstep = (size_t)BB * 64;

    barrier_lgkm();

    #pragma unroll 2
    for (int sl = 0; sl < CS; ++sl) {
        const int par = sl & 1;
        ushort_t* shc = smem + par * (NB * SH_STR);
        ushort_t* shn = smem + (par ^ 1) * (NB * SH_STR);

        short8 af0 = *(const short8*)&shc[m * SH_STR + q * 8];
        short8 af1 = *(const short8*)&shc[m * SH_STR + 32 + q * 8];

        f32x4 g[4];
        #pragma unroll
        for (int a = 0; a < 4; ++a) {
            g[a][0] = bflo(upf[par][a].x); g[a][1] = bfhi(upf[par][a].x);
            g[a][2] = bflo(upf[par][a].y); g[a][3] = bfhi(upf[par][a].y);
        }
        {
            int snext = (sl + 2 < CS) ? (sl + 2) : sl;
            const uint_t* pn = wx + (size_t)(snext * 256 + bg) * 2048 + l * 2;
            #pragma unroll
            for (int a = 0; a < 4; ++a)
                upf[par][a] = *(const uint2*)(pn + (w + 4 * a) * 128);
        }

        #pragma unroll
        for (int a = 0; a < 4; ++a) {
            g[a] = __builtin_amdgcn_mfma_f32_16x16x32_bf16(af0, whhf[a][0], g[a], 0, 0, 0);
            g[a] = __builtin_amdgcn_mfma_f32_16x16x32_bf16(af1, whhf[a][1], g[a], 0, 0, 0);
        }

        #pragma unroll
        for (int r = 0; r < 4; ++r) {
            float gi = fsig(g[0][r]);
            float gf = fsig(g[1][r]);
            float gg = ftanh(g[2][r]);
            float go = fsig(g[3][r]);
            float c  = gf * creg[r] + gi * gg;
            creg[r] = c;
            float h = go * ftanh(c);
            hlast[r] = h;
            ushort_t hb = f2bf(h);
            shn[(q * 4 + r) * SH_STR + 16 * w + m] = hb;
            hsp[(size_t)sl * hstep + r * 64] = hb;    // global, off-chain
        }

        barrier_lgkm();
    }

    if (!last) {
        const int jcol = 16 * w + m;
        #pragma unroll
        for (int r = 0; r < 4; ++r)
            hws[(size_t)bg * 1024 + (q * 4 + r) * 64 + jcol] = f2bf(hlast[r]);
        float4 cv; cv.x = creg[0]; cv.y = creg[1]; cv.z = creg[2]; cv.w = creg[3];
        *(float4*)(cws + ((size_t)bg * 256 + t) * 4) = cv;
    } else {
        const int jcol = 16 * w + m;
        #pragma unroll
        for (int r = 0; r < 4; ++r) {
            int row = b0 + q * 4 + r;
            out[BB * SS + (size_t)row * 64 + jcol]           = hlast[r];
            out[BB * SS + BB * 64 + (size_t)row * 64 + jcol] = creg[r];
        }
    }
}

// ============================================================================
// Deferred value head block (device fn): 16 rows per block.
// ============================================================================
__device__ __forceinline__ void val_block(
    const ushort_t* __restrict__ hseq, const float* __restrict__ Wv,
    const float* __restrict__ bv, float* __restrict__ out, int c0, int vb)
{
    const int t = threadIdx.x;
    const int lane16 = t & 15;
    const int row = vb * 16 + (t >> 4);               // [0, CS*BB)
    float4 wv = *(const float4*)(Wv + lane16 * 4);
    uint2 hv = *(const uint2*)(hseq + (size_t)row * 64 + lane16 * 4);
    float pv = bflo(hv.x) * wv.x + bfhi(hv.x) * wv.y
             + bflo(hv.y) * wv.z + bfhi(hv.y) * wv.w;
    pv += __shfl_xor(pv, 1, 64);
    pv += __shfl_xor(pv, 2, 64);
    pv += __shfl_xor(pv, 4, 64);
    pv += __shfl_xor(pv, 8, 64);
    if (lane16 == 0) {
        int sl = row >> 12, b = row & 4095;
        out[(size_t)b * SS + c0 + sl] = pv + bv[0];
    }
}

// ============================================================================
// Combined pipeline dispatch: [0,nrec) rec(c) | [nrec,nrec+nenc) enc(c+1) |
// rest val(c-1). No intra-dispatch dependencies (wx + hseq double-buffered).
// ============================================================================
__global__ __launch_bounds__(NT, 4)
void podcritic_step(const float* __restrict__ self_obs, const float* __restrict__ tm_obs,
                    const float* __restrict__ en_obs,   const float* __restrict__ cp_obs,
                    const float* __restrict__ b1, const float* __restrict__ b2,
                    const float* __restrict__ bih, const float* __restrict__ bhh,
                    const short8* __restrict__ img,
                    uint_t* __restrict__ wx_enc, const uint_t* __restrict__ wx_rec,
                    ushort_t* __restrict__ hws, float* __restrict__ cws,
                    ushort_t* __restrict__ hseq_rec, const ushort_t* __restrict__ hseq_val,
                    const float* __restrict__ Wv, const float* __restrict__ bv,
                    float* __restrict__ out,
                    int enc_c0, int val_c0, int nrec, int nenc, int first, int last)
{
    __shared__ __align__(16) ushort_t smem[ENC_LDS_USHORTS];
    const int bid = blockIdx.x;
    if (bid < nrec) {
        rec_block(smem, img + 160 * 64, wx_rec, hws, cws, hseq_rec, out, first, last);
    } else if (bid < nrec + nenc) {
        enc_block(smem, self_obs, tm_obs, en_obs, cp_obs, b1, b2, bih, bhh,
                  img, wx_enc, enc_c0, bid - nrec);
    } else {
        val_block(hseq_val, Wv, bv, out, val_c0, bid - nrec - nenc);
    }
}

// ============================================================================
// Fallback: fused kernel (only if ws too small) — round-2 structure.
// ============================================================================
__global__ __launch_bounds__(NT, 1)
void podcritic_mfma(const float* __restrict__ self_obs,
                    const float* __restrict__ tm_obs,
                    const float* __restrict__ en_obs,
                    const float* __restrict__ cp_obs,
                    const float* __restrict__ W1, const float* __restrict__ b1,
                    const float* __restrict__ W2, const float* __restrict__ b2,
                    const float* __restrict__ Wih, const float* __restrict__ bih,
                    const float* __restrict__ Whh, const float* __restrict__ bhh,
                    const float* __restrict__ Wv, const float* __restrict__ bv,
                    float* __restrict__ out)
{
    __shared__ __align__(16) ushort_t sx[2][NB * SX_STR];
    __shared__ __align__(16) ushort_t sh1[NB * SH1_STR];
    __shared__ __align__(16) ushort_t semb[NB * SEMB_STR];
    __shared__ __align__(16) ushort_t sh[NB * SH_STR];
    __shared__ float sWv[64];

    const int t  = threadIdx.x;
    const int w  = t >> 6;
    const int l  = t & 63;
    const int q  = l >> 4;
    const int m  = l & 15;
    const int b0 = blockIdx.x * NB;

    short8 w1f[4][2];
    short8 w2f[2][8];
    short8 wihf[4][4];
    short8 whhf[4][2];
    float bias1[4], bias2[2], bg[4];

    #pragma unroll
    for (int i = 0; i < 4; ++i) {
        int n = w * 64 + i * 16 + m;
        bias1[i] = b1[n];
        #pragma unroll
        for (int kk = 0; kk < 2; ++kk) {
            FragU u;
            #pragma unroll
            for (int j = 0; j < 8; ++j) {
                int k = kk * 32 + q * 8 + j;
                u.u[j] = f2bf(k < 47 ? W1[k * 256 + n] : 0.f);
            }
            w1f[i][kk] = u.v;
        }
    }
    #pragma unroll
    for (int i = 0; i < 2; ++i) {
        int n = 32 * w + i * 16 + m;
        bias2[i] = b2[n];
        #pragma unroll
        for (int kk = 0; kk < 8; ++kk) {
            FragU u;
            #pragma unroll
            for (int j = 0; j < 8; ++j) {
                int k = kk * 32 + q * 8 + j;
                u.u[j] = f2bf(W2[k * 128 + n]);
            }
            w2f[i][kk] = u.v;
        }
    }
    #pragma unroll
    for (int i = 0; i < 4; ++i) {
        int n = (w + 4 * i) * 16 + m;
        bg[i] = bih[n] + bhh[n];
        #pragma unroll
        for (int kk = 0; kk < 4; ++kk) {
            FragU u;
            #pragma unroll
            for (int j = 0; j < 8; ++j) {
                int k = kk * 32 + q * 8 + j;
                u.u[j] = f2bf(Wih[k * 256 + n]);
            }
            wihf[i][kk] = u.v;
        }
        #pragma unroll
        for (int kk = 0; kk < 2; ++kk) {
            FragU u;
            #pragma unroll
            for (int j = 0; j < 8; ++j) {
                int k = kk * 32 + q * 8 + j;
                u.u[j] = f2bf(Whh[k * 256 + n]);
            }
            whhf[i][kk] = u.v;
        }
    }
    const float bvv = bv[0];
    if (t < 64) sWv[t] = Wv[t];

    for (int idx = t; idx < NB * SH_STR; idx += NT) sh[idx] = 0;

    const int pcol = t & 63;
    const int prow = t >> 6;
    #pragma unroll
    for (int j = 0; j < 4; ++j) {
        int r  = 4 * j + prow;
        int bs = (b0 + r) * SS + 0;
        float v = 0.f;
        if (pcol < 15)      v = self_obs[bs * 15 + pcol];
        else if (pcol < 28) v = tm_obs[bs * 13 + (pcol - 15)];
        else if (pcol < 41) { int kk = pcol - 28;
                              v = 0.5f * (en_obs[(bs * 2) * 13 + kk] + en_obs[(bs * 2) * 13 + 13 + kk]); }
        else if (pcol < 47) v = cp_obs[bs * 6 + (pcol - 41)];
        sx[0][r * SX_STR + pcol] = f2bf(v);
    }
    __syncthreads();

    float creg[4] = {0.f, 0.f, 0.f, 0.f};
    float hreg[4] = {0.f, 0.f, 0.f, 0.f};
    int cur = 0;

    for (int s = 0; s < SS; ++s) {
        float pf[4];
        #pragma unroll
        for (int j = 0; j < 4; ++j) {
            float v = 0.f;
            if (s + 1 < SS) {
                int r  = 4 * j + prow;
                int bs = (b0 + r) * SS + (s + 1);
                if (pcol < 15)      v = self_obs[bs * 15 + pcol];
                else if (pcol < 28) v = tm_obs[bs * 13 + (pcol - 15)];
                else if (pcol < 41) { int kk = pcol - 28;
                                      v = 0.5f * (en_obs[(bs * 2) * 13 + kk] + en_obs[(bs * 2) * 13 + 13 + kk]); }
                else if (pcol < 47) v = cp_obs[bs * 6 + (pcol - 41)];
            }
            pf[j] = v;
        }

        {
            f32x4 c1[4] = {{0,0,0,0},{0,0,0,0},{0,0,0,0},{0,0,0,0}};
            #pragma unroll
            for (int kk = 0; kk < 2; ++kk) {
                short8 a = *(const short8*)&sx[cur][m * SX_STR + kk * 32 + q * 8];
                #pragma unroll
                for (int i = 0; i < 4; ++i)
                    c1[i] = __builtin_amdgcn_mfma_f32_16x16x32_bf16(a, w1f[i][kk], c1[i], 0, 0, 0);
            }
            #pragma unroll
            for (int i = 0; i < 4; ++i) {
                int col = w * 64 + i * 16 + m;
                #pragma unroll
                for (int r = 0; r < 4; ++r)
                    sh1[(q * 4 + r) * SH1_STR + col] = f2bf(fmaxf(c1[i][r] + bias1[i], 0.f));
            }
        }
        __syncthreads();

        {
            f32x4 c2[2] = {{0,0,0,0},{0,0,0,0}};
            #pragma unroll
            for (int kk = 0; kk < 8; ++kk) {
                short8 a = *(const short8*)&sh1[m * SH1_STR + kk * 32 + q * 8];
                #pragma unroll
                for (int i = 0; i < 2; ++i)
                    c2[i] = __builtin_amdgcn_mfma_f32_16x16x32_bf16(a, w2f[i][kk], c2[i], 0, 0, 0);
            }
            #pragma unroll
            for (int i = 0; i < 2; ++i) {
                int col = 32 * w + i * 16 + m;
                #pragma unroll
                for (int r = 0; r < 4; ++r)
                    semb[(q * 4 + r) * SEMB_STR + col] = f2bf(fmaxf(c2[i][r] + bias2[i], 0.f));
            }
        }
        __syncthreads();

        {
            f32x4 g[4];
            #pragma unroll
            for (int i = 0; i < 4; ++i) g[i] = (f32x4){bg[i], bg[i], bg[i], bg[i]};
            #pragma unroll
            for (int kk = 0; kk < 4; ++kk) {
                short8 a = *(const short8*)&semb[m * SEMB_STR + kk * 32 + q * 8];
                #pragma unroll
                for (int i = 0; i < 4; ++i)
                    g[i] = __builtin_amdgcn_mfma_f32_16x16x32_bf16(a, wihf[i][kk], g[i], 0, 0, 0);
            }
            #pragma unroll
            for (int kk = 0; kk < 2; ++kk) {
                short8 a = *(const short8*)&sh[m * SH_STR + kk * 32 + q * 8];
                #pragma unroll
                for (int i = 0; i < 4; ++i)
                    g[i] = __builtin_amdgcn_mfma_f32_16x16x32_bf16(a, whhf[i][kk], g[i], 0, 0, 0);
            }
            const int jcol = 16 * w + m;
            #pragma unroll
            for (int r = 0; r < 4; ++r) {
                float gi = fsig(g[0][r]);
                float gf = fsig(g[1][r]);
                float gg = ftanh(g[2][r]);
                float go = fsig(g[3][r]);
                float c  = gf * creg[r] + gi * gg;
                creg[r] = c;
                float h = go * ftanh(c);
                hreg[r] = h;
                sh[(q * 4 + r) * SH_STR + jcol] = f2bf(h);
            }
            #pragma unroll
            for (int j = 0; j < 4; ++j) {
                int r = 4 * j + prow;
                sx[cur ^ 1][r * SX_STR + pcol] = f2bf(pf[j]);
            }
        }
        __syncthreads();

        {
            int r = t >> 4, pp = t & 15;
            const ushort_t* hp = &sh[r * SH_STR + pp * 4];
            float pv = 0.f;
            #pragma unroll
            for (int j = 0; j < 4; ++j) pv += bf2f(hp[j]) * sWv[pp * 4 + j];
            pv += __shfl_xor(pv, 1, 16);
            pv += __shfl_xor(pv, 2, 16);
            pv += __shfl_xor(pv, 4, 16);
            pv += __shfl_xor(pv, 8, 16);
            if (pp == 0) out[(b0 + r) * SS + s] = pv + bvv;
        }
        cur ^= 1;
    }

    {
        const int jcol = 16 * w + m;
        #pragma unroll
        for (int r = 0; r < 4; ++r) {
            int row = b0 + q * 4 + r;
            out[BB * SS + row * 64 + jcol]           = hreg[r];
            out[BB * SS + BB * 64 + row * 64 + jcol] = creg[r];
        }
    }
}

extern "C" void kernel_launch(void* const* d_in, const int* in_sizes, int n_in,
                              void* d_out, int out_size, void* d_ws, size_t ws_size,
                              hipStream_t stream) {
    const float* self_obs = (const float*)d_in[0];
    const float* tm_obs   = (const float*)d_in[1];
    const float* en_obs   = (const float*)d_in[2];
    const float* cp_obs   = (const float*)d_in[3];
    const float* W1  = (const float*)d_in[4];
    const float* b1  = (const float*)d_in[5];
    const float* W2  = (const float*)d_in[6];
    const float* b2  = (const float*)d_in[7];
    const float* Wih = (const float*)d_in[8];
    const float* bih = (const float*)d_in[9];
    const float* Whh = (const float*)d_in[10];
    const float* bhh = (const float*)d_in[11];
    const float* Wv  = (const float*)d_in[12];
    const float* bv  = (const float*)d_in[13];
    float* out = (float*)d_out;

    // ws layout (double-buffered wx + hseq)
    const size_t wx_chunk   = (size_t)CS * 256 * 2048 * 4;   // 33,554,432
    const size_t h_bytes    = 256 * 1024 * 2;                // 524,288
    const size_t c_bytes    = 256 * 1024 * 4;                // 1,048,576
    const size_t img_bytes  = 192 * 64 * 16;                 // 196,608
    const size_t hseq_chunk = (size_t)CS * BB * 64 * 2;      // 8,388,608
    const size_t need = 2 * wx_chunk + h_bytes + c_bytes + img_bytes + 2 * hseq_chunk; // 85,655,552

    if (ws_size >= need) {
        char* p = (char*)d_ws;
        uint_t*   wxb[2]   = { (uint_t*)p, (uint_t*)(p + wx_chunk) };
        ushort_t* hws      = (ushort_t*)(p + 2 * wx_chunk);
        float*    cws      = (float*)(p + 2 * wx_chunk + h_bytes);
        short8*   img      = (short8*)(p + 2 * wx_chunk + h_bytes + c_bytes);
        ushort_t* hseqb[2] = { (ushort_t*)(p + 2 * wx_chunk + h_bytes + c_bytes + img_bytes),
                               (ushort_t*)(p + 2 * wx_chunk + h_bytes + c_bytes + img_bytes + hseq_chunk) };

        podcritic_prep<<<48, NT, 0, stream>>>(W1, W2, Wih, Whh, img);

        // head: enc chunk 0 alone
        podcritic_step<<<2048, NT, 0, stream>>>(
            self_obs, tm_obs, en_obs, cp_obs, b1, b2, bih, bhh, img,
            wxb[0], wxb[0], hws, cws, hseqb[0], hseqb[0], Wv, bv, out,
            /*enc_c0=*/0, /*val_c0=*/0, /*nrec=*/0, /*nenc=*/2048, 0, 0);

        for (int c = 0; c < NCH; ++c) {
            int nenc = (c + 1 < NCH) ? 2048 : 0;
            int nval = (c > 0) ? 4096 : 0;
            int grid = 256 + nenc + nval;
            podcritic_step<<<grid, NT, 0, stream>>>(
                self_obs, tm_obs, en_obs, cp_obs, b1, b2, bih, bhh, img,
                wxb[(c + 1) & 1], wxb[c & 1], hws, cws,
                hseqb[c & 1], hseqb[(c > 0 ? (c - 1) : 0) & 1], Wv, bv, out,
                /*enc_c0=*/(c + 1) * CS, /*val_c0=*/(c - 1) * CS,
                /*nrec=*/256, nenc, (c == 0) ? 1 : 0, (c == NCH - 1) ? 1 : 0);
        }
        // tail: val for last chunk
        podcritic_step<<<4096, NT, 0, stream>>>(
            self_obs, tm_obs, en_obs, cp_obs, b1, b2, bih, bhh, img,
            wxb[0], wxb[0], hws, cws, hseqb[0], hseqb[(NCH - 1) & 1], Wv, bv, out,
            /*enc_c0=*/0, /*val_c0=*/(NCH - 1) * CS, /*nrec=*/0, /*nenc=*/0, 0, 0);
    } else {
        podcritic_mfma<<<BB / NB, NT, 0, stream>>>(
            self_obs, tm_obs, en_obs, cp_obs,
            W1, b1, W2, b2, Wih, bih, Whh, bhh, Wv, bv, out);
    }
}